// Round 1
// baseline (843.793 us; speedup 1.0000x reference)
//
#include <hip/hip_runtime.h>

#define FEAT 2048
#define HWD 14
#define NPIX 196          // 14*14
#define C_CLS 20
#define M_DIM 64
#define U_DIM 128
#define B_SZ 4
#define K_REL 19          // C-1
#define NPOOL 49          // 7*7

// ---------------------------------------------------------------------------
// Kernel 1: x_tmp[b,c,m,hw] = sum_f x[b,f,hw] * W_parcel[c,m,f]
// GEMM view: A = W_parcel (1280 x 2048) row-major, B = x (2048 x 784 with
// col n = b*196+hw), rows = (c,m) with m fast (block row == class c).
// ---------------------------------------------------------------------------
__global__ __launch_bounds__(256) void gemm1_kernel(
        const float* __restrict__ x, const float* __restrict__ Wp,
        float* __restrict__ x_tmp) {
    const int BK = 16;
    __shared__ float As[BK][64 + 1];
    __shared__ float Bs[BK][64 + 2];
    const int tid = threadIdx.x;
    const int c  = blockIdx.y;            // row tile == class (M=64 == BM)
    const int n0 = blockIdx.x * 64;

    // B staging: thread handles column nb, 4 k-rows per iter
    const int ncol = tid & 63;
    const int nb = n0 + ncol;
    const int kr0 = tid >> 6;             // 0..3
    const bool nvalid = nb < B_SZ * NPIX;
    const int bb = nvalid ? nb / NPIX : 0;
    const int hwb = nvalid ? nb % NPIX : 0;
    const float* xb = x + (size_t)bb * FEAT * NPIX + hwb;

    // A staging: thread loads one float4 per iter
    const int arow = tid >> 2;            // 0..63
    const int kq = tid & 3;               // 0..3
    const float* Ap = Wp + ((size_t)c * M_DIM + arow) * FEAT + kq * 4;

    float acc[4][4];
#pragma unroll
    for (int i = 0; i < 4; i++)
#pragma unroll
        for (int j = 0; j < 4; j++) acc[i][j] = 0.f;

    const int ty = tid >> 4;              // 0..15
    const int tx = tid & 15;              // 0..15

    for (int k0 = 0; k0 < FEAT; k0 += BK) {
        float4 av = *(const float4*)(Ap + k0);
        As[kq * 4 + 0][arow] = av.x;
        As[kq * 4 + 1][arow] = av.y;
        As[kq * 4 + 2][arow] = av.z;
        As[kq * 4 + 3][arow] = av.w;
#pragma unroll
        for (int j = 0; j < 4; j++) {
            int kk = kr0 + j * 4;
            float v = nvalid ? xb[(size_t)(k0 + kk) * NPIX] : 0.f;
            Bs[kk][ncol] = v;
        }
        __syncthreads();
#pragma unroll
        for (int kk = 0; kk < BK; kk++) {
            float a[4], bv[4];
#pragma unroll
            for (int j = 0; j < 4; j++) a[j] = As[kk][ty * 4 + j];
#pragma unroll
            for (int j = 0; j < 4; j++) bv[j] = Bs[kk][tx * 4 + j];
#pragma unroll
            for (int i = 0; i < 4; i++)
#pragma unroll
                for (int j = 0; j < 4; j++) acc[i][j] += a[i] * bv[j];
        }
        __syncthreads();
    }
#pragma unroll
    for (int i = 0; i < 4; i++) {
        int m = ty * 4 + i;
#pragma unroll
        for (int j = 0; j < 4; j++) {
            int n = n0 + tx * 4 + j;
            if (n < B_SZ * NPIX) {
                int b = n / NPIX, hw = n % NPIX;
                x_tmp[(((size_t)b * C_CLS + c) * M_DIM + m) * NPIX + hw] = acc[i][j];
            }
        }
    }
}

// ---------------------------------------------------------------------------
// Kernel 2: pooled[b,c,m,p] = max2x2(relu(x_tmp))  (p = ph*7+pw)
// ---------------------------------------------------------------------------
__global__ __launch_bounds__(256) void pool_kernel(
        const float* __restrict__ x_tmp, float* __restrict__ pooled) {
    int idx = blockIdx.x * 256 + threadIdx.x;   // B*C*M*49 = 250880 exact
    int p = idx % NPOOL;
    int m = (idx / NPOOL) % M_DIM;
    int c = (idx / (NPOOL * M_DIM)) % C_CLS;
    int b = idx / (NPOOL * M_DIM * C_CLS);
    int ph = p / 7, pw = p % 7;
    const float* base = x_tmp + (((size_t)b * C_CLS + c) * M_DIM + m) * NPIX
                        + (ph * 2) * HWD + pw * 2;
    float v = fmaxf(fmaxf(base[0], base[1]), fmaxf(base[HWD], base[HWD + 1]));
    pooled[idx] = fmaxf(v, 0.f);
}

// ---------------------------------------------------------------------------
// Kernel 3: theta[b,c,j] = sum_k pooled_flat[b,c,k]*W_stn[c,j,k] + b_stn[c,j]
// ---------------------------------------------------------------------------
__global__ __launch_bounds__(256) void theta_kernel(
        const float* __restrict__ pooled, const float* __restrict__ Wstn,
        const float* __restrict__ bstn, float* __restrict__ theta) {
    const int KFLAT = M_DIM * NPOOL;   // 3136
    int bc = blockIdx.x;               // b*C + c
    int c = bc % C_CLS;
    int tid = threadIdx.x;
    const float* flat = pooled + (size_t)bc * KFLAT;
    float s[6] = {0, 0, 0, 0, 0, 0};
    for (int k = tid; k < KFLAT; k += 256) {
        float f = flat[k];
#pragma unroll
        for (int j = 0; j < 6; j++) s[j] += f * Wstn[((size_t)c * 6 + j) * KFLAT + k];
    }
    __shared__ float red[6][256];
#pragma unroll
    for (int j = 0; j < 6; j++) red[j][tid] = s[j];
    __syncthreads();
    for (int off = 128; off > 0; off >>= 1) {
        if (tid < off) {
#pragma unroll
            for (int j = 0; j < 6; j++) red[j][tid] += red[j][tid + off];
        }
        __syncthreads();
    }
    if (tid < 6) theta[bc * 6 + tid] = red[tid][0] + bstn[c * 6 + tid];
}

// ---------------------------------------------------------------------------
// Kernel 4: bilinear grid sample. x_obj[b,c,m,hw] from x_tmp[b,c,m,:,:]
// ---------------------------------------------------------------------------
__global__ __launch_bounds__(256) void sample_kernel(
        const float* __restrict__ x_tmp, const float* __restrict__ theta,
        float* __restrict__ x_obj) {
    int idx = blockIdx.x * 256 + threadIdx.x;   // B*C*M*196 = 1003520 exact
    int hw = idx % NPIX;
    int m = (idx / NPIX) % M_DIM;
    int c = (idx / (NPIX * M_DIM)) % C_CLS;
    int b = idx / (NPIX * M_DIM * C_CLS);
    const float* th = theta + ((size_t)b * C_CLS + c) * 6;
    int w = hw % HWD, h = hw / HWD;
    float fx = -1.f + w * (2.f / 13.f);
    float fy = -1.f + h * (2.f / 13.f);
    float gxn = th[0] * fx + th[1] * fy + th[2];
    float gyn = th[3] * fx + th[4] * fy + th[5];
    float gx = (gxn + 1.f) * 0.5f * (HWD - 1);
    float gy = (gyn + 1.f) * 0.5f * (HWD - 1);
    float x0f = floorf(gx), y0f = floorf(gy);
    int x0 = (int)x0f, y0 = (int)y0f;
    int x1 = x0 + 1, y1 = y0 + 1;
    const float* img = x_tmp + (((size_t)b * C_CLS + c) * M_DIM + m) * NPIX;

    auto gat = [&](int yi, int xi) -> float {
        bool v = (yi >= 0) & (yi < HWD) & (xi >= 0) & (xi < HWD);
        int yc = min(max(yi, 0), HWD - 1);
        int xc = min(max(xi, 0), HWD - 1);
        return v ? img[yc * HWD + xc] : 0.f;
    };
    float xw1 = (float)x1 - gx, xw0 = gx - (float)x0;
    float yw1 = (float)y1 - gy, yw0 = gy - (float)y0;
    x_obj[idx] = gat(y0, x0) * xw1 * yw1 + gat(y0, x1) * xw0 * yw1 +
                 gat(y1, x0) * xw1 * yw0 + gat(y1, x1) * xw0 * yw0;
}

// ---------------------------------------------------------------------------
// Kernel 5: relation. Block = (k, c, b). Computes, for all u and hw:
//   s = sum_m Wa[c,k,u,m]*x_obj[b,c,m,hw] + Wb[c,k,u,m]*x_obj[b,kj,m,hw]
// then partial[b,c,k,u] = sum_hw relu(s).
// x_obj slices staged in LDS in two 32-row m-halves (fp32).
// ---------------------------------------------------------------------------
#define HWPAD 208   // 16*13
__global__ __launch_bounds__(512) void relation_kernel(
        const float* __restrict__ x_obj, const float* __restrict__ Wg,
        float* __restrict__ partial) {
    __shared__ float sc[32][HWPAD];
    __shared__ float sk[32][HWPAD];
    const int k = blockIdx.x;      // 0..18
    const int c = blockIdx.y;      // 0..19
    const int b = blockIdx.z;      // 0..3
    const int kj = (k < c) ? k : k + 1;
    const int tid = threadIdx.x;
    const int tx = tid & 15;       // hw group
    const int ug = tid >> 4;       // 0..31, u0 = ug*4

    const float* xc_g = x_obj + (((size_t)b * C_CLS + c) * M_DIM) * NPIX;
    const float* xk_g = x_obj + (((size_t)b * C_CLS + kj) * M_DIM) * NPIX;
    // Wg: (C, 19, U, 2M); Wa = [..., :64], Wb = [..., 64:]
    const float* wbase = Wg + (((size_t)c * K_REL + k) * U_DIM + ug * 4) * (2 * M_DIM);

    float tmp[4][13];
#pragma unroll
    for (int uu = 0; uu < 4; uu++)
#pragma unroll
        for (int i = 0; i < 13; i++) tmp[uu][i] = 0.f;

    for (int mh = 0; mh < 2; mh++) {
        __syncthreads();
        for (int i = tid; i < 32 * HWPAD; i += 512) {
            int m = i / HWPAD, hwp = i % HWPAD;
            float vc = 0.f, vk = 0.f;
            if (hwp < NPIX) {
                vc = xc_g[(size_t)(mh * 32 + m) * NPIX + hwp];
                vk = xk_g[(size_t)(mh * 32 + m) * NPIX + hwp];
            }
            sc[m][hwp] = vc;
            sk[m][hwp] = vk;
        }
        __syncthreads();
#pragma unroll 2
        for (int m4 = 0; m4 < 8; m4++) {
            float4 wa4[4], wb4[4];
#pragma unroll
            for (int uu = 0; uu < 4; uu++) {
                const float* wp = wbase + (size_t)uu * (2 * M_DIM) + mh * 32 + m4 * 4;
                wa4[uu] = *(const float4*)(wp);
                wb4[uu] = *(const float4*)(wp + M_DIM);
            }
#pragma unroll
            for (int mi = 0; mi < 4; mi++) {
                int sm = m4 * 4 + mi;
                float xcv[13], xkv[13];
#pragma unroll
                for (int i = 0; i < 13; i++) {
                    xcv[i] = sc[sm][tx * 13 + i];
                    xkv[i] = sk[sm][tx * 13 + i];
                }
#pragma unroll
                for (int uu = 0; uu < 4; uu++) {
                    float wa = (mi == 0) ? wa4[uu].x : (mi == 1) ? wa4[uu].y
                               : (mi == 2) ? wa4[uu].z : wa4[uu].w;
                    float wb = (mi == 0) ? wb4[uu].x : (mi == 1) ? wb4[uu].y
                               : (mi == 2) ? wb4[uu].z : wb4[uu].w;
#pragma unroll
                    for (int i = 0; i < 13; i++)
                        tmp[uu][i] += wa * xcv[i] + wb * xkv[i];
                }
            }
        }
    }
    // relu + reduce over hw (pad columns hold exact 0 -> relu contributes 0)
    float s[4];
#pragma unroll
    for (int uu = 0; uu < 4; uu++) {
        float acc = 0.f;
#pragma unroll
        for (int i = 0; i < 13; i++) acc += fmaxf(tmp[uu][i], 0.f);
        s[uu] = acc;
    }
#pragma unroll
    for (int mask = 1; mask < 16; mask <<= 1) {
#pragma unroll
        for (int uu = 0; uu < 4; uu++) s[uu] += __shfl_xor(s[uu], mask, 64);
    }
    if (tx == 0) {
        float* pp = partial + (((size_t)b * C_CLS + c) * K_REL + k) * U_DIM + ug * 4;
#pragma unroll
        for (int uu = 0; uu < 4; uu++) pp[uu] = s[uu];
    }
}

// ---------------------------------------------------------------------------
// Kernel 6: out[b,c] = (sum_u (sum_k partial[b,c,k,u]) * w_phi[u]) / 196 + b_phi
// ---------------------------------------------------------------------------
__global__ __launch_bounds__(128) void final_kernel(
        const float* __restrict__ partial, const float* __restrict__ wphi,
        const float* __restrict__ bphi, float* __restrict__ out) {
    int bc = blockIdx.x;
    int u = threadIdx.x;
    float s = 0.f;
    for (int k = 0; k < K_REL; k++)
        s += partial[((size_t)bc * K_REL + k) * U_DIM + u];
    s *= wphi[u];
    __shared__ float red[128];
    red[u] = s;
    __syncthreads();
    for (int off = 64; off > 0; off >>= 1) {
        if (u < off) red[u] += red[u + off];
        __syncthreads();
    }
    if (u == 0) out[bc] = red[0] / (float)NPIX + bphi[0];
}

// ---------------------------------------------------------------------------
extern "C" void kernel_launch(void* const* d_in, const int* in_sizes, int n_in,
                              void* d_out, int out_size, void* d_ws, size_t ws_size,
                              hipStream_t stream) {
    const float* x    = (const float*)d_in[0];
    const float* Wp   = (const float*)d_in[1];
    const float* Wstn = (const float*)d_in[2];
    const float* bstn = (const float*)d_in[3];
    const float* Wg   = (const float*)d_in[4];
    const float* wphi = (const float*)d_in[5];
    const float* bphi = (const float*)d_in[6];
    float* out = (float*)d_out;
    float* ws = (float*)d_ws;

    float* x_tmp   = ws;                    // 1,003,520 floats
    float* x_obj   = ws + 1003520;          // 1,003,520
    float* pooled  = ws + 2007040;          //   250,880
    float* theta   = ws + 2257920;          //       480
    float* partial = ws + 2258400;          //   194,560  (total ~9.8 MB)

    dim3 g1(13, 20);
    gemm1_kernel<<<g1, 256, 0, stream>>>(x, Wp, x_tmp);
    pool_kernel<<<980, 256, 0, stream>>>(x_tmp, pooled);
    theta_kernel<<<80, 256, 0, stream>>>(pooled, Wstn, bstn, theta);
    sample_kernel<<<3920, 256, 0, stream>>>(x_tmp, theta, x_obj);
    dim3 gr(K_REL, C_CLS, B_SZ);
    relation_kernel<<<gr, 512, 0, stream>>>(x_obj, Wg, partial);
    final_kernel<<<80, 128, 0, stream>>>(partial, wphi, bphi, out);
}

// Round 2
// 276.229 us; speedup vs baseline: 3.0547x; 3.0547x over previous
//
#include <hip/hip_runtime.h>

#define FEAT 2048
#define HWD 14
#define NPIX 196          // 14*14
#define C_CLS 20
#define M_DIM 64
#define U_DIM 128
#define B_SZ 4
#define K_REL 19          // C-1
#define NPOOL 49          // 7*7

typedef __attribute__((ext_vector_type(8))) short bf16x8s;
typedef __attribute__((ext_vector_type(4))) float f32x4;
typedef __attribute__((ext_vector_type(4))) unsigned int uint4v;

__device__ inline unsigned short f2bf(float f) {
    unsigned u = __builtin_bit_cast(unsigned, f);
    unsigned r = (u + 0x7FFF + ((u >> 16) & 1)) >> 16;   // RNE
    return (unsigned short)r;
}

// ---------------------------------------------------------------------------
// Kernel 1: x_tmp[b,c,m,hw] = sum_f x[b,f,hw] * W_parcel[c,m,f]   (fp32)
// ---------------------------------------------------------------------------
__global__ __launch_bounds__(256) void gemm1_kernel(
        const float* __restrict__ x, const float* __restrict__ Wp,
        float* __restrict__ x_tmp) {
    const int BK = 16;
    __shared__ float As[BK][64 + 1];
    __shared__ float Bs[BK][64 + 2];
    const int tid = threadIdx.x;
    const int c  = blockIdx.y;
    const int n0 = blockIdx.x * 64;

    const int ncol = tid & 63;
    const int nb = n0 + ncol;
    const int kr0 = tid >> 6;
    const bool nvalid = nb < B_SZ * NPIX;
    const int bb = nvalid ? nb / NPIX : 0;
    const int hwb = nvalid ? nb % NPIX : 0;
    const float* xb = x + (size_t)bb * FEAT * NPIX + hwb;

    const int arow = tid >> 2;
    const int kq = tid & 3;
    const float* Ap = Wp + ((size_t)c * M_DIM + arow) * FEAT + kq * 4;

    float acc[4][4];
#pragma unroll
    for (int i = 0; i < 4; i++)
#pragma unroll
        for (int j = 0; j < 4; j++) acc[i][j] = 0.f;

    const int ty = tid >> 4;
    const int tx = tid & 15;

    for (int k0 = 0; k0 < FEAT; k0 += BK) {
        float4 av = *(const float4*)(Ap + k0);
        As[kq * 4 + 0][arow] = av.x;
        As[kq * 4 + 1][arow] = av.y;
        As[kq * 4 + 2][arow] = av.z;
        As[kq * 4 + 3][arow] = av.w;
#pragma unroll
        for (int j = 0; j < 4; j++) {
            int kk = kr0 + j * 4;
            float v = nvalid ? xb[(size_t)(k0 + kk) * NPIX] : 0.f;
            Bs[kk][ncol] = v;
        }
        __syncthreads();
#pragma unroll
        for (int kk = 0; kk < BK; kk++) {
            float a[4], bv[4];
#pragma unroll
            for (int j = 0; j < 4; j++) a[j] = As[kk][ty * 4 + j];
#pragma unroll
            for (int j = 0; j < 4; j++) bv[j] = Bs[kk][tx * 4 + j];
#pragma unroll
            for (int i = 0; i < 4; i++)
#pragma unroll
                for (int j = 0; j < 4; j++) acc[i][j] += a[i] * bv[j];
        }
        __syncthreads();
    }
#pragma unroll
    for (int i = 0; i < 4; i++) {
        int m = ty * 4 + i;
#pragma unroll
        for (int j = 0; j < 4; j++) {
            int n = n0 + tx * 4 + j;
            if (n < B_SZ * NPIX) {
                int b = n / NPIX, hw = n % NPIX;
                x_tmp[(((size_t)b * C_CLS + c) * M_DIM + m) * NPIX + hw] = acc[i][j];
            }
        }
    }
}

// ---------------------------------------------------------------------------
// Kernel 1b: Wg fp32 -> bf16 cast
// ---------------------------------------------------------------------------
__global__ __launch_bounds__(256) void cvt_kernel(
        const float* __restrict__ src, unsigned short* __restrict__ dst, int n4) {
    int i = blockIdx.x * 256 + threadIdx.x;
    if (i < n4) {
        float4 v = *(const float4*)(src + (size_t)i * 4);
        ushort4 o;
        o.x = f2bf(v.x); o.y = f2bf(v.y); o.z = f2bf(v.z); o.w = f2bf(v.w);
        *(ushort4*)(dst + (size_t)i * 4) = o;
    }
}

// ---------------------------------------------------------------------------
// Kernel 2: pooled[b,c,m,p] = max2x2(relu(x_tmp))
// ---------------------------------------------------------------------------
__global__ __launch_bounds__(256) void pool_kernel(
        const float* __restrict__ x_tmp, float* __restrict__ pooled) {
    int idx = blockIdx.x * 256 + threadIdx.x;
    int p = idx % NPOOL;
    int m = (idx / NPOOL) % M_DIM;
    int c = (idx / (NPOOL * M_DIM)) % C_CLS;
    int b = idx / (NPOOL * M_DIM * C_CLS);
    int ph = p / 7, pw = p % 7;
    const float* base = x_tmp + (((size_t)b * C_CLS + c) * M_DIM + m) * NPIX
                        + (ph * 2) * HWD + pw * 2;
    float v = fmaxf(fmaxf(base[0], base[1]), fmaxf(base[HWD], base[HWD + 1]));
    pooled[idx] = fmaxf(v, 0.f);
}

// ---------------------------------------------------------------------------
// Kernel 3: theta
// ---------------------------------------------------------------------------
__global__ __launch_bounds__(256) void theta_kernel(
        const float* __restrict__ pooled, const float* __restrict__ Wstn,
        const float* __restrict__ bstn, float* __restrict__ theta) {
    const int KFLAT = M_DIM * NPOOL;   // 3136
    int bc = blockIdx.x;
    int c = bc % C_CLS;
    int tid = threadIdx.x;
    const float* flat = pooled + (size_t)bc * KFLAT;
    float s[6] = {0, 0, 0, 0, 0, 0};
    for (int k = tid; k < KFLAT; k += 256) {
        float f = flat[k];
#pragma unroll
        for (int j = 0; j < 6; j++) s[j] += f * Wstn[((size_t)c * 6 + j) * KFLAT + k];
    }
    __shared__ float red[6][256];
#pragma unroll
    for (int j = 0; j < 6; j++) red[j][tid] = s[j];
    __syncthreads();
    for (int off = 128; off > 0; off >>= 1) {
        if (tid < off) {
#pragma unroll
            for (int j = 0; j < 6; j++) red[j][tid] += red[j][tid + off];
        }
        __syncthreads();
    }
    if (tid < 6) theta[bc * 6 + tid] = red[tid][0] + bstn[c * 6 + tid];
}

// ---------------------------------------------------------------------------
// Kernel 4: bilinear grid sample -> x_objT[b,c,hw,m] in bf16 (transposed!)
// thread mapping: m fastest for coalesced transposed stores.
// ---------------------------------------------------------------------------
__global__ __launch_bounds__(256) void sampleT_kernel(
        const float* __restrict__ x_tmp, const float* __restrict__ theta,
        unsigned short* __restrict__ x_objT) {
    int idx = blockIdx.x * 256 + threadIdx.x;   // B*C*NPIX*64 = 1,003,520
    int m = idx & 63;
    int hw = (idx >> 6) % NPIX;
    int c = (idx / (64 * NPIX)) % C_CLS;
    int b = idx / (64 * NPIX * C_CLS);
    const float* th = theta + ((size_t)b * C_CLS + c) * 6;
    int w = hw % HWD, h = hw / HWD;
    float fx = -1.f + w * (2.f / 13.f);
    float fy = -1.f + h * (2.f / 13.f);
    float gxn = th[0] * fx + th[1] * fy + th[2];
    float gyn = th[3] * fx + th[4] * fy + th[5];
    float gx = (gxn + 1.f) * 0.5f * (HWD - 1);
    float gy = (gyn + 1.f) * 0.5f * (HWD - 1);
    float x0f = floorf(gx), y0f = floorf(gy);
    int x0 = (int)x0f, y0 = (int)y0f;
    int x1 = x0 + 1, y1 = y0 + 1;
    const float* img = x_tmp + (((size_t)b * C_CLS + c) * M_DIM + m) * NPIX;

    auto gat = [&](int yi, int xi) -> float {
        bool v = (yi >= 0) & (yi < HWD) & (xi >= 0) & (xi < HWD);
        int yc = min(max(yi, 0), HWD - 1);
        int xc = min(max(xi, 0), HWD - 1);
        return v ? img[yc * HWD + xc] : 0.f;
    };
    float xw1 = (float)x1 - gx, xw0 = gx - (float)x0;
    float yw1 = (float)y1 - gy, yw0 = gy - (float)y0;
    float val = gat(y0, x0) * xw1 * yw1 + gat(y0, x1) * xw0 * yw1 +
                gat(y1, x0) * xw1 * yw0 + gat(y1, x1) * xw0 * yw0;
    x_objT[(((size_t)b * C_CLS + c) * NPIX + hw) * 64 + m] = f2bf(val);
}

// ---------------------------------------------------------------------------
// Kernel 5: relation via MFMA. Block = (k, c, b), 256 threads = 4 waves.
// Per block: S[128u][208hw] = W'[128u][128m'] * X'[128m'][208hw], m' = [xc;xk]
// relu, column-sum over hw -> partial[b,c,k,u].
// X' staged in LDS transposed: Xs[hw][m'] rows padded to 136 bf16 (272 B,
// stride 68 words -> 2-way bank aliasing = free).
// ---------------------------------------------------------------------------
#define MP 136
__global__ __launch_bounds__(256) void relation_mfma_kernel(
        const unsigned short* __restrict__ x_objT,
        const unsigned short* __restrict__ Wgbf,
        float* __restrict__ partial) {
    __shared__ unsigned short Xs[208 * MP];   // 56,576 B
    const int k = blockIdx.x;      // 0..18
    const int c = blockIdx.y;      // 0..19
    const int b = blockIdx.z;      // 0..3
    const int kj = (k < c) ? k : k + 1;
    const int tid = threadIdx.x;
    const int lane = tid & 63;
    const int wv = tid >> 6;       // 0..3
    const int l15 = lane & 15;
    const int lq = lane >> 4;      // 0..3

    // A-fragments: 2 u-tiles x 4 k-steps, 16B contiguous per lane.
    // Wgbf[c,k,u,m'] with m' contiguous (Wa|Wb already adjacent).
    bf16x8s AF[2][4];
    const unsigned short* wb = Wgbf + (((size_t)c * K_REL + k) * U_DIM) * (2 * M_DIM);
#pragma unroll
    for (int ut = 0; ut < 2; ut++) {
        int u = wv * 32 + ut * 16 + l15;
#pragma unroll
        for (int ks = 0; ks < 4; ks++)
            AF[ut][ks] = *(const bf16x8s*)(wb + (size_t)u * 128 + ks * 32 + lq * 8);
    }

    // Stage Xs[hw][m']: 208 rows x 16 chunks of 8 bf16. chunk<8 -> xc, else xk.
    const unsigned short* xc = x_objT + ((size_t)(b * C_CLS + c)) * NPIX * 64;
    const unsigned short* xk = x_objT + ((size_t)(b * C_CLS + kj)) * NPIX * 64;
#pragma unroll
    for (int it = 0; it < 13; it++) {
        int i = tid + it * 256;            // 0..3327
        int hw = i >> 4, ch = i & 15;
        uint4v v = {0, 0, 0, 0};
        if (hw < NPIX) {
            const unsigned short* src = (ch < 8 ? xc : xk) + (size_t)hw * 64 + (ch & 7) * 8;
            v = *(const uint4v*)src;
        }
        *(uint4v*)(&Xs[hw * MP + ch * 8]) = v;   // m' = ch*8
    }
    __syncthreads();

    float csum[2][4];
#pragma unroll
    for (int ut = 0; ut < 2; ut++)
#pragma unroll
        for (int r = 0; r < 4; r++) csum[ut][r] = 0.f;

    for (int t = 0; t < 13; t++) {
        bf16x8s BF[4];
#pragma unroll
        for (int ks = 0; ks < 4; ks++)
            BF[ks] = *(const bf16x8s*)(&Xs[(t * 16 + l15) * MP + ks * 32 + lq * 8]);
        f32x4 acc0 = {0.f, 0.f, 0.f, 0.f}, acc1 = {0.f, 0.f, 0.f, 0.f};
#pragma unroll
        for (int ks = 0; ks < 4; ks++) {
            acc0 = __builtin_amdgcn_mfma_f32_16x16x32_bf16(AF[0][ks], BF[ks], acc0, 0, 0, 0);
            acc1 = __builtin_amdgcn_mfma_f32_16x16x32_bf16(AF[1][ks], BF[ks], acc1, 0, 0, 0);
        }
#pragma unroll
        for (int r = 0; r < 4; r++) {
            csum[0][r] += fmaxf(acc0[r], 0.f);
            csum[1][r] += fmaxf(acc1[r], 0.f);
        }
    }
    // Reduce over hw-columns: lanes 0..15 within each 16-lane group hold cols.
#pragma unroll
    for (int mask = 1; mask < 16; mask <<= 1) {
#pragma unroll
        for (int ut = 0; ut < 2; ut++)
#pragma unroll
            for (int r = 0; r < 4; r++)
                csum[ut][r] += __shfl_xor(csum[ut][r], mask, 64);
    }
    if (l15 == 0) {
        float* pp = partial + (((size_t)b * C_CLS + c) * K_REL + k) * U_DIM;
#pragma unroll
        for (int ut = 0; ut < 2; ut++)
#pragma unroll
            for (int r = 0; r < 4; r++)
                pp[wv * 32 + ut * 16 + lq * 4 + r] = csum[ut][r];
    }
}

// ---------------------------------------------------------------------------
// Kernel 6: out[b,c]
// ---------------------------------------------------------------------------
__global__ __launch_bounds__(128) void final_kernel(
        const float* __restrict__ partial, const float* __restrict__ wphi,
        const float* __restrict__ bphi, float* __restrict__ out) {
    int bc = blockIdx.x;
    int u = threadIdx.x;
    float s = 0.f;
    for (int k = 0; k < K_REL; k++)
        s += partial[((size_t)bc * K_REL + k) * U_DIM + u];
    s *= wphi[u];
    __shared__ float red[128];
    red[u] = s;
    __syncthreads();
    for (int off = 64; off > 0; off >>= 1) {
        if (u < off) red[u] += red[u + off];
        __syncthreads();
    }
    if (u == 0) out[bc] = red[0] / (float)NPIX + bphi[0];
}

// ---------------------------------------------------------------------------
extern "C" void kernel_launch(void* const* d_in, const int* in_sizes, int n_in,
                              void* d_out, int out_size, void* d_ws, size_t ws_size,
                              hipStream_t stream) {
    const float* x    = (const float*)d_in[0];
    const float* Wp   = (const float*)d_in[1];
    const float* Wstn = (const float*)d_in[2];
    const float* bstn = (const float*)d_in[3];
    const float* Wg   = (const float*)d_in[4];
    const float* wphi = (const float*)d_in[5];
    const float* bphi = (const float*)d_in[6];
    float* out = (float*)d_out;
    char* wsb = (char*)d_ws;

    float* x_tmp            = (float*)(wsb);                  // 4,014,080 B
    float* pooled           = (float*)(wsb + 4014080);        // 1,003,520 B
    float* theta            = (float*)(wsb + 5017600);        //     1,920 B
    float* partial          = (float*)(wsb + 5019648);        //   778,240 B
    unsigned short* x_objT  = (unsigned short*)(wsb + 5797888);  // 2,007,040 B
    unsigned short* Wgbf    = (unsigned short*)(wsb + 7804928);  // 12,451,840 B
    // total 20,256,768 B

    dim3 g1(13, 20);
    gemm1_kernel<<<g1, 256, 0, stream>>>(x, Wp, x_tmp);
    const int WG_N4 = C_CLS * K_REL * U_DIM * 2 * M_DIM / 4;  // 1,556,480
    cvt_kernel<<<(WG_N4 + 255) / 256, 256, 0, stream>>>(Wg, Wgbf, WG_N4);
    pool_kernel<<<980, 256, 0, stream>>>(x_tmp, pooled);
    theta_kernel<<<80, 256, 0, stream>>>(pooled, Wstn, bstn, theta);
    sampleT_kernel<<<3920, 256, 0, stream>>>(x_tmp, theta, x_objT);
    dim3 gr(K_REL, C_CLS, B_SZ);
    relation_mfma_kernel<<<gr, 256, 0, stream>>>(x_objT, Wgbf, partial);
    final_kernel<<<80, 128, 0, stream>>>(partial, wphi, bphi, out);
}

// Round 3
// 100.604 us; speedup vs baseline: 8.3873x; 2.7457x over previous
//
#include <hip/hip_runtime.h>

#define FEAT 2048
#define HWD 14
#define NPIX 196          // 14*14
#define C_CLS 20
#define M_DIM 64
#define U_DIM 128
#define B_SZ 4
#define K_REL 19          // C-1
#define NPOOL 49          // 7*7

typedef __attribute__((ext_vector_type(8))) short bf16x8s;
typedef __attribute__((ext_vector_type(8))) unsigned short ushort8v;
typedef __attribute__((ext_vector_type(4))) float f32x4;
typedef __attribute__((ext_vector_type(4))) unsigned int uint4v;

__device__ inline unsigned short f2bf(float f) {
    unsigned u = __builtin_bit_cast(unsigned, f);
    unsigned r = (u + 0x7FFF + ((u >> 16) & 1)) >> 16;   // RNE
    return (unsigned short)r;
}

__device__ inline bf16x8s cvt8(const float* __restrict__ p) {
    float4 lo = *(const float4*)p;
    float4 hi = *(const float4*)(p + 4);
    bf16x8s r;
    r[0] = (short)f2bf(lo.x); r[1] = (short)f2bf(lo.y);
    r[2] = (short)f2bf(lo.z); r[3] = (short)f2bf(lo.w);
    r[4] = (short)f2bf(hi.x); r[5] = (short)f2bf(hi.y);
    r[6] = (short)f2bf(hi.z); r[7] = (short)f2bf(hi.w);
    return r;
}

// ---------------------------------------------------------------------------
// Kernel 0: transpose+cvt  x[b][f][hw] f32 -> xTb[b][hw(208,zero-pad)][f] bf16
// ---------------------------------------------------------------------------
__global__ __launch_bounds__(256) void xt_kernel(
        const float* __restrict__ x, unsigned short* __restrict__ xTb) {
    __shared__ unsigned short T[64][210];
    const int k0 = blockIdx.x * 64;     // FEAT/64 = 32 tiles
    const int b = blockIdx.y;
    const int tid = threadIdx.x;
    const float* xb = x + ((size_t)b * FEAT + k0) * NPIX;
    for (int i = tid; i < 64 * NPIX; i += 256) {
        int kk = i / NPIX, hw = i - kk * NPIX;
        T[kk][hw] = f2bf(xb[(size_t)kk * NPIX + hw]);
    }
    __syncthreads();
    for (int i = tid; i < 208 * 8; i += 256) {
        int hw = i >> 3, ch = i & 7;
        ushort8v o;
#pragma unroll
        for (int j = 0; j < 8; j++)
            o[j] = (hw < NPIX) ? T[ch * 8 + j][hw] : (unsigned short)0;
        *(ushort8v*)(xTb + ((size_t)b * 208 + hw) * FEAT + k0 + ch * 8) = o;
    }
}

// ---------------------------------------------------------------------------
// Kernel 1: MFMA GEMM  x_tmp[b,c,m,hw] += sum_k Wp[c,m,k]*xTb[b,hw,k]
// Block=(c,b,khalf): 64 rows x 208 cols, BK=64, 16 K-steps, dbuf LDS B-tile.
// A-frags direct from global fp32 (cvt in reg). Output via atomicAdd (2-way
// K-split, x_tmp pre-zeroed -> deterministic).
// ---------------------------------------------------------------------------
#define KP 72    // LDS row stride (bf16): 144 B, 16B-aligned, conflict-free
__global__ __launch_bounds__(256) void gemm1_mfma_kernel(
        const unsigned short* __restrict__ xTb,
        const float* __restrict__ Wp,
        float* __restrict__ x_tmp) {
    __shared__ unsigned short Xs[2][208 * KP];
    const int c = blockIdx.x, b = blockIdx.y, kh = blockIdx.z;
    const int tid = threadIdx.x;
    const int lane = tid & 63, wv = tid >> 6;
    const int l15 = lane & 15, lq = lane >> 4;
    const int NSTEP = 16;  // 16*64 = 1024 = K/2
    const unsigned short* xb = xTb + (size_t)b * 208 * FEAT + kh * 1024;
    const float* wb = Wp + ((size_t)(c * M_DIM + wv * 16 + l15)) * FEAT
                      + kh * 1024 + lq * 8;

    uint4v sreg[7];
    auto g_issue = [&](int s) {
#pragma unroll
        for (int it = 0; it < 7; it++) {
            int i = tid + it * 256;
            if (i < 1664)
                sreg[it] = *(const uint4v*)(xb + (size_t)(i >> 3) * FEAT + s * 64 + (i & 7) * 8);
        }
    };
    auto l_write = [&](int buf) {
#pragma unroll
        for (int it = 0; it < 7; it++) {
            int i = tid + it * 256;
            if (i < 1664)
                *(uint4v*)(&Xs[buf][(i >> 3) * KP + (i & 7) * 8]) = sreg[it];
        }
    };

    f32x4 acc[13];
#pragma unroll
    for (int t = 0; t < 13; t++) acc[t] = (f32x4){0.f, 0.f, 0.f, 0.f};

    // prolog
    g_issue(0);
    bf16x8s AF0 = cvt8(wb);
    bf16x8s AF1 = cvt8(wb + 32);
    l_write(0);
    __syncthreads();

    for (int s = 0; s < NSTEP; s++) {
        if (s + 1 < NSTEP) g_issue(s + 1);
        bf16x8s A0 = AF0, A1 = AF1;
        if (s + 1 < NSTEP) {
            AF0 = cvt8(wb + (s + 1) * 64);
            AF1 = cvt8(wb + (s + 1) * 64 + 32);
        }
        const unsigned short* Xb = Xs[s & 1];
#pragma unroll
        for (int t = 0; t < 13; t++) {
            bf16x8s B0 = *(const bf16x8s*)(&Xb[(t * 16 + l15) * KP + lq * 8]);
            bf16x8s B1 = *(const bf16x8s*)(&Xb[(t * 16 + l15) * KP + 32 + lq * 8]);
            acc[t] = __builtin_amdgcn_mfma_f32_16x16x32_bf16(A0, B0, acc[t], 0, 0, 0);
            acc[t] = __builtin_amdgcn_mfma_f32_16x16x32_bf16(A1, B1, acc[t], 0, 0, 0);
        }
        if (s + 1 < NSTEP) l_write((s + 1) & 1);
        __syncthreads();
    }

    // epilogue: C row = wv*16 + lq*4 + r, col = t*16 + l15
    float* outb = x_tmp + ((size_t)(b * C_CLS + c) * M_DIM + wv * 16 + lq * 4) * NPIX;
#pragma unroll
    for (int t = 0; t < 13; t++) {
        int hw = t * 16 + l15;
        if (hw < NPIX) {
#pragma unroll
            for (int r = 0; r < 4; r++)
                atomicAdd(&outb[(size_t)r * NPIX + hw], acc[t][r]);
        }
    }
}

// ---------------------------------------------------------------------------
// Kernel 2: pooled[b,c,m,p] = max2x2(relu(x_tmp))
// ---------------------------------------------------------------------------
__global__ __launch_bounds__(256) void pool_kernel(
        const float* __restrict__ x_tmp, float* __restrict__ pooled) {
    int idx = blockIdx.x * 256 + threadIdx.x;
    int p = idx % NPOOL;
    int m = (idx / NPOOL) % M_DIM;
    int c = (idx / (NPOOL * M_DIM)) % C_CLS;
    int b = idx / (NPOOL * M_DIM * C_CLS);
    int ph = p / 7, pw = p % 7;
    const float* base = x_tmp + (((size_t)b * C_CLS + c) * M_DIM + m) * NPIX
                        + (ph * 2) * HWD + pw * 2;
    float v = fmaxf(fmaxf(base[0], base[1]), fmaxf(base[HWD], base[HWD + 1]));
    pooled[idx] = fmaxf(v, 0.f);
}

// ---------------------------------------------------------------------------
// Kernel 3: theta
// ---------------------------------------------------------------------------
__global__ __launch_bounds__(256) void theta_kernel(
        const float* __restrict__ pooled, const float* __restrict__ Wstn,
        const float* __restrict__ bstn, float* __restrict__ theta) {
    const int KFLAT = M_DIM * NPOOL;   // 3136
    int bc = blockIdx.x;
    int c = bc % C_CLS;
    int tid = threadIdx.x;
    const float* flat = pooled + (size_t)bc * KFLAT;
    float s[6] = {0, 0, 0, 0, 0, 0};
    for (int k = tid; k < KFLAT; k += 256) {
        float f = flat[k];
#pragma unroll
        for (int j = 0; j < 6; j++) s[j] += f * Wstn[((size_t)c * 6 + j) * KFLAT + k];
    }
    __shared__ float red[6][256];
#pragma unroll
    for (int j = 0; j < 6; j++) red[j][tid] = s[j];
    __syncthreads();
    for (int off = 128; off > 0; off >>= 1) {
        if (tid < off) {
#pragma unroll
            for (int j = 0; j < 6; j++) red[j][tid] += red[j][tid + off];
        }
        __syncthreads();
    }
    if (tid < 6) theta[bc * 6 + tid] = red[tid][0] + bstn[c * 6 + tid];
}

// ---------------------------------------------------------------------------
// Kernel 4: bilinear grid sample -> x_objT[b,c,hw,m] bf16 (transposed)
// ---------------------------------------------------------------------------
__global__ __launch_bounds__(256) void sampleT_kernel(
        const float* __restrict__ x_tmp, const float* __restrict__ theta,
        unsigned short* __restrict__ x_objT) {
    int idx = blockIdx.x * 256 + threadIdx.x;   // B*C*NPIX*64 = 1,003,520
    int m = idx & 63;
    int hw = (idx >> 6) % NPIX;
    int c = (idx / (64 * NPIX)) % C_CLS;
    int b = idx / (64 * NPIX * C_CLS);
    const float* th = theta + ((size_t)b * C_CLS + c) * 6;
    int w = hw % HWD, h = hw / HWD;
    float fx = -1.f + w * (2.f / 13.f);
    float fy = -1.f + h * (2.f / 13.f);
    float gxn = th[0] * fx + th[1] * fy + th[2];
    float gyn = th[3] * fx + th[4] * fy + th[5];
    float gx = (gxn + 1.f) * 0.5f * (HWD - 1);
    float gy = (gyn + 1.f) * 0.5f * (HWD - 1);
    float x0f = floorf(gx), y0f = floorf(gy);
    int x0 = (int)x0f, y0 = (int)y0f;
    int x1 = x0 + 1, y1 = y0 + 1;
    const float* img = x_tmp + (((size_t)b * C_CLS + c) * M_DIM + m) * NPIX;

    auto gat = [&](int yi, int xi) -> float {
        bool v = (yi >= 0) & (yi < HWD) & (xi >= 0) & (xi < HWD);
        int yc = min(max(yi, 0), HWD - 1);
        int xc = min(max(xi, 0), HWD - 1);
        return v ? img[yc * HWD + xc] : 0.f;
    };
    float xw1 = (float)x1 - gx, xw0 = gx - (float)x0;
    float yw1 = (float)y1 - gy, yw0 = gy - (float)y0;
    float val = gat(y0, x0) * xw1 * yw1 + gat(y0, x1) * xw0 * yw1 +
                gat(y1, x0) * xw1 * yw0 + gat(y1, x1) * xw0 * yw0;
    x_objT[(((size_t)b * C_CLS + c) * NPIX + hw) * 64 + m] = f2bf(val);
}

// ---------------------------------------------------------------------------
// Kernel 5: relation via MFMA. Block=(k,c,b), 4 waves. Wg read fp32, cvt once.
// ---------------------------------------------------------------------------
#define MP 136
__global__ __launch_bounds__(256) void relation_mfma_kernel(
        const unsigned short* __restrict__ x_objT,
        const float* __restrict__ Wg,
        float* __restrict__ partial) {
    __shared__ unsigned short Xs[208 * MP];   // 56,576 B
    const int k = blockIdx.x;
    const int c = blockIdx.y;
    const int b = blockIdx.z;
    const int kj = (k < c) ? k : k + 1;
    const int tid = threadIdx.x;
    const int lane = tid & 63;
    const int wv = tid >> 6;
    const int l15 = lane & 15;
    const int lq = lane >> 4;

    bf16x8s AF[2][4];
    const float* wgb = Wg + (((size_t)c * K_REL + k) * U_DIM) * (2 * M_DIM);
#pragma unroll
    for (int ut = 0; ut < 2; ut++) {
        int u = wv * 32 + ut * 16 + l15;
#pragma unroll
        for (int ks = 0; ks < 4; ks++)
            AF[ut][ks] = cvt8(wgb + (size_t)u * 128 + ks * 32 + lq * 8);
    }

    const unsigned short* xc = x_objT + ((size_t)(b * C_CLS + c)) * NPIX * 64;
    const unsigned short* xk = x_objT + ((size_t)(b * C_CLS + kj)) * NPIX * 64;
#pragma unroll
    for (int it = 0; it < 13; it++) {
        int i = tid + it * 256;            // 0..3327
        int hw = i >> 4, ch = i & 15;
        uint4v v = {0, 0, 0, 0};
        if (hw < NPIX) {
            const unsigned short* src = (ch < 8 ? xc : xk) + (size_t)hw * 64 + (ch & 7) * 8;
            v = *(const uint4v*)src;
        }
        *(uint4v*)(&Xs[hw * MP + ch * 8]) = v;
    }
    __syncthreads();

    float csum[2][4];
#pragma unroll
    for (int ut = 0; ut < 2; ut++)
#pragma unroll
        for (int r = 0; r < 4; r++) csum[ut][r] = 0.f;

    for (int t = 0; t < 13; t++) {
        bf16x8s BF[4];
#pragma unroll
        for (int ks = 0; ks < 4; ks++)
            BF[ks] = *(const bf16x8s*)(&Xs[(t * 16 + l15) * MP + ks * 32 + lq * 8]);
        f32x4 acc0 = {0.f, 0.f, 0.f, 0.f}, acc1 = {0.f, 0.f, 0.f, 0.f};
#pragma unroll
        for (int ks = 0; ks < 4; ks++) {
            acc0 = __builtin_amdgcn_mfma_f32_16x16x32_bf16(AF[0][ks], BF[ks], acc0, 0, 0, 0);
            acc1 = __builtin_amdgcn_mfma_f32_16x16x32_bf16(AF[1][ks], BF[ks], acc1, 0, 0, 0);
        }
#pragma unroll
        for (int r = 0; r < 4; r++) {
            csum[0][r] += fmaxf(acc0[r], 0.f);
            csum[1][r] += fmaxf(acc1[r], 0.f);
        }
    }
#pragma unroll
    for (int mask = 1; mask < 16; mask <<= 1) {
#pragma unroll
        for (int ut = 0; ut < 2; ut++)
#pragma unroll
            for (int r = 0; r < 4; r++)
                csum[ut][r] += __shfl_xor(csum[ut][r], mask, 64);
    }
    if (l15 == 0) {
        float* pp = partial + (((size_t)b * C_CLS + c) * K_REL + k) * U_DIM;
#pragma unroll
        for (int ut = 0; ut < 2; ut++)
#pragma unroll
            for (int r = 0; r < 4; r++)
                pp[wv * 32 + ut * 16 + lq * 4 + r] = csum[ut][r];
    }
}

// ---------------------------------------------------------------------------
// Kernel 6: out[b,c]
// ---------------------------------------------------------------------------
__global__ __launch_bounds__(128) void final_kernel(
        const float* __restrict__ partial, const float* __restrict__ wphi,
        const float* __restrict__ bphi, float* __restrict__ out) {
    int bc = blockIdx.x;
    int u = threadIdx.x;
    float s = 0.f;
    for (int k = 0; k < K_REL; k++)
        s += partial[((size_t)bc * K_REL + k) * U_DIM + u];
    s *= wphi[u];
    __shared__ float red[128];
    red[u] = s;
    __syncthreads();
    for (int off = 64; off > 0; off >>= 1) {
        if (u < off) red[u] += red[u + off];
        __syncthreads();
    }
    if (u == 0) out[bc] = red[0] / (float)NPIX + bphi[0];
}

// ---------------------------------------------------------------------------
extern "C" void kernel_launch(void* const* d_in, const int* in_sizes, int n_in,
                              void* d_out, int out_size, void* d_ws, size_t ws_size,
                              hipStream_t stream) {
    const float* x    = (const float*)d_in[0];
    const float* Wp   = (const float*)d_in[1];
    const float* Wstn = (const float*)d_in[2];
    const float* bstn = (const float*)d_in[3];
    const float* Wg   = (const float*)d_in[4];
    const float* wphi = (const float*)d_in[5];
    const float* bphi = (const float*)d_in[6];
    float* out = (float*)d_out;
    char* wsb = (char*)d_ws;

    float* x_tmp           = (float*)(wsb);                      // 4,014,080 B
    unsigned short* xTb    = (unsigned short*)(wsb + 4014080);   // 3,407,872 B
    float* pooled          = (float*)(wsb + 7421952);            // 1,003,520 B
    float* theta           = (float*)(wsb + 8425472);            //     1,920 B
    float* partial         = (float*)(wsb + 8427392);            //   778,240 B
    unsigned short* x_objT = (unsigned short*)(wsb + 9205632);   // 2,007,040 B
    // total 11,212,672 B

    hipMemsetAsync(x_tmp, 0, 4014080, stream);
    xt_kernel<<<dim3(32, 4), 256, 0, stream>>>(x, xTb);
    gemm1_mfma_kernel<<<dim3(20, 4, 2), 256, 0, stream>>>(xTb, Wp, x_tmp);
    pool_kernel<<<980, 256, 0, stream>>>(x_tmp, pooled);
    theta_kernel<<<80, 256, 0, stream>>>(pooled, Wstn, bstn, theta);
    sampleT_kernel<<<3920, 256, 0, stream>>>(x_tmp, theta, x_objT);
    dim3 gr(K_REL, C_CLS, B_SZ);
    relation_mfma_kernel<<<gr, 256, 0, stream>>>(x_objT, Wg, partial);
    final_kernel<<<80, 128, 0, stream>>>(partial, wphi, bphi, out);
}

// Round 4
// 99.827 us; speedup vs baseline: 8.4526x; 1.0078x over previous
//
#include <hip/hip_runtime.h>

#define FEAT 2048
#define HWD 14
#define NPIX 196          // 14*14
#define C_CLS 20
#define M_DIM 64
#define U_DIM 128
#define B_SZ 4
#define K_REL 19          // C-1
#define NPOOL 49          // 7*7

typedef __attribute__((ext_vector_type(8))) short bf16x8s;
typedef __attribute__((ext_vector_type(8))) unsigned short ushort8v;
typedef __attribute__((ext_vector_type(4))) float f32x4;
typedef __attribute__((ext_vector_type(4))) unsigned int uint4v;

__device__ inline unsigned short f2bf(float f) {
    unsigned u = __builtin_bit_cast(unsigned, f);
    unsigned r = (u + 0x7FFF + ((u >> 16) & 1)) >> 16;   // RNE
    return (unsigned short)r;
}

__device__ inline bf16x8s cvt8(const float* __restrict__ p) {
    float4 lo = *(const float4*)p;
    float4 hi = *(const float4*)(p + 4);
    bf16x8s r;
    r[0] = (short)f2bf(lo.x); r[1] = (short)f2bf(lo.y);
    r[2] = (short)f2bf(lo.z); r[3] = (short)f2bf(lo.w);
    r[4] = (short)f2bf(hi.x); r[5] = (short)f2bf(hi.y);
    r[6] = (short)f2bf(hi.z); r[7] = (short)f2bf(hi.w);
    return r;
}

// ---------------------------------------------------------------------------
// Kernel Z: fast zero of x_tmp (runtime fillBuffer is ~0.1 TB/s here).
// 250,880 float4 = 4,014,080 B, one 16 B store per thread.
// ---------------------------------------------------------------------------
__global__ __launch_bounds__(256) void zero_kernel(float* __restrict__ p) {
    int i = blockIdx.x * 256 + threadIdx.x;   // grid 980*256 = 250,880 exact
    *(f32x4*)(p + (size_t)i * 4) = (f32x4){0.f, 0.f, 0.f, 0.f};
}

// ---------------------------------------------------------------------------
// Kernel 0: transpose+cvt  x[b][f][hw] f32 -> xTb[b][hw(208,zero-pad)][f] bf16
// ---------------------------------------------------------------------------
__global__ __launch_bounds__(256) void xt_kernel(
        const float* __restrict__ x, unsigned short* __restrict__ xTb) {
    __shared__ unsigned short T[64][210];
    const int k0 = blockIdx.x * 64;     // FEAT/64 = 32 tiles
    const int b = blockIdx.y;
    const int tid = threadIdx.x;
    const float* xb = x + ((size_t)b * FEAT + k0) * NPIX;
    for (int i = tid; i < 64 * NPIX; i += 256) {
        int kk = i / NPIX, hw = i - kk * NPIX;
        T[kk][hw] = f2bf(xb[(size_t)kk * NPIX + hw]);
    }
    __syncthreads();
    for (int i = tid; i < 208 * 8; i += 256) {
        int hw = i >> 3, ch = i & 7;
        ushort8v o;
#pragma unroll
        for (int j = 0; j < 8; j++)
            o[j] = (hw < NPIX) ? T[ch * 8 + j][hw] : (unsigned short)0;
        *(ushort8v*)(xTb + ((size_t)b * 208 + hw) * FEAT + k0 + ch * 8) = o;
    }
}

// ---------------------------------------------------------------------------
// Kernel 1: MFMA GEMM  x_tmp[b,c,m,hw] += sum_k Wp[c,m,k]*xTb[b,hw,k]
// Block=(c,b,khalf): 64 rows x 208 cols, BK=64, 16 K-steps, dbuf LDS B-tile.
// A-frags direct from global fp32 (cvt in reg). Output via atomicAdd (2-way
// K-split, x_tmp pre-zeroed -> deterministic).
// ---------------------------------------------------------------------------
#define KP 72    // LDS row stride (bf16): 144 B, 16B-aligned, conflict-free
__global__ __launch_bounds__(256) void gemm1_mfma_kernel(
        const unsigned short* __restrict__ xTb,
        const float* __restrict__ Wp,
        float* __restrict__ x_tmp) {
    __shared__ unsigned short Xs[2][208 * KP];
    const int c = blockIdx.x, b = blockIdx.y, kh = blockIdx.z;
    const int tid = threadIdx.x;
    const int lane = tid & 63, wv = tid >> 6;
    const int l15 = lane & 15, lq = lane >> 4;
    const int NSTEP = 16;  // 16*64 = 1024 = K/2
    const unsigned short* xb = xTb + (size_t)b * 208 * FEAT + kh * 1024;
    const float* wb = Wp + ((size_t)(c * M_DIM + wv * 16 + l15)) * FEAT
                      + kh * 1024 + lq * 8;

    uint4v sreg[7];
    auto g_issue = [&](int s) {
#pragma unroll
        for (int it = 0; it < 7; it++) {
            int i = tid + it * 256;
            if (i < 1664)
                sreg[it] = *(const uint4v*)(xb + (size_t)(i >> 3) * FEAT + s * 64 + (i & 7) * 8);
        }
    };
    auto l_write = [&](int buf) {
#pragma unroll
        for (int it = 0; it < 7; it++) {
            int i = tid + it * 256;
            if (i < 1664)
                *(uint4v*)(&Xs[buf][(i >> 3) * KP + (i & 7) * 8]) = sreg[it];
        }
    };

    f32x4 acc[13];
#pragma unroll
    for (int t = 0; t < 13; t++) acc[t] = (f32x4){0.f, 0.f, 0.f, 0.f};

    // prolog
    g_issue(0);
    bf16x8s AF0 = cvt8(wb);
    bf16x8s AF1 = cvt8(wb + 32);
    l_write(0);
    __syncthreads();

    for (int s = 0; s < NSTEP; s++) {
        if (s + 1 < NSTEP) g_issue(s + 1);
        bf16x8s A0 = AF0, A1 = AF1;
        if (s + 1 < NSTEP) {
            AF0 = cvt8(wb + (s + 1) * 64);
            AF1 = cvt8(wb + (s + 1) * 64 + 32);
        }
        const unsigned short* Xb = Xs[s & 1];
#pragma unroll
        for (int t = 0; t < 13; t++) {
            bf16x8s B0 = *(const bf16x8s*)(&Xb[(t * 16 + l15) * KP + lq * 8]);
            bf16x8s B1 = *(const bf16x8s*)(&Xb[(t * 16 + l15) * KP + 32 + lq * 8]);
            acc[t] = __builtin_amdgcn_mfma_f32_16x16x32_bf16(A0, B0, acc[t], 0, 0, 0);
            acc[t] = __builtin_amdgcn_mfma_f32_16x16x32_bf16(A1, B1, acc[t], 0, 0, 0);
        }
        if (s + 1 < NSTEP) l_write((s + 1) & 1);
        __syncthreads();
    }

    // epilogue: C row = wv*16 + lq*4 + r, col = t*16 + l15
    float* outb = x_tmp + ((size_t)(b * C_CLS + c) * M_DIM + wv * 16 + lq * 4) * NPIX;
#pragma unroll
    for (int t = 0; t < 13; t++) {
        int hw = t * 16 + l15;
        if (hw < NPIX) {
#pragma unroll
            for (int r = 0; r < 4; r++)
                atomicAdd(&outb[(size_t)r * NPIX + hw], acc[t][r]);
        }
    }
}

// ---------------------------------------------------------------------------
// Kernel 2: pooled[b,c,m,p] = max2x2(relu(x_tmp))
// ---------------------------------------------------------------------------
__global__ __launch_bounds__(256) void pool_kernel(
        const float* __restrict__ x_tmp, float* __restrict__ pooled) {
    int idx = blockIdx.x * 256 + threadIdx.x;
    int p = idx % NPOOL;
    int m = (idx / NPOOL) % M_DIM;
    int c = (idx / (NPOOL * M_DIM)) % C_CLS;
    int b = idx / (NPOOL * M_DIM * C_CLS);
    int ph = p / 7, pw = p % 7;
    const float* base = x_tmp + (((size_t)b * C_CLS + c) * M_DIM + m) * NPIX
                        + (ph * 2) * HWD + pw * 2;
    float v = fmaxf(fmaxf(base[0], base[1]), fmaxf(base[HWD], base[HWD + 1]));
    pooled[idx] = fmaxf(v, 0.f);
}

// ---------------------------------------------------------------------------
// Kernel 3: theta
// ---------------------------------------------------------------------------
__global__ __launch_bounds__(256) void theta_kernel(
        const float* __restrict__ pooled, const float* __restrict__ Wstn,
        const float* __restrict__ bstn, float* __restrict__ theta) {
    const int KFLAT = M_DIM * NPOOL;   // 3136
    int bc = blockIdx.x;
    int c = bc % C_CLS;
    int tid = threadIdx.x;
    const float* flat = pooled + (size_t)bc * KFLAT;
    float s[6] = {0, 0, 0, 0, 0, 0};
    for (int k = tid; k < KFLAT; k += 256) {
        float f = flat[k];
#pragma unroll
        for (int j = 0; j < 6; j++) s[j] += f * Wstn[((size_t)c * 6 + j) * KFLAT + k];
    }
    __shared__ float red[6][256];
#pragma unroll
    for (int j = 0; j < 6; j++) red[j][tid] = s[j];
    __syncthreads();
    for (int off = 128; off > 0; off >>= 1) {
        if (tid < off) {
#pragma unroll
            for (int j = 0; j < 6; j++) red[j][tid] += red[j][tid + off];
        }
        __syncthreads();
    }
    if (tid < 6) theta[bc * 6 + tid] = red[tid][0] + bstn[c * 6 + tid];
}

// ---------------------------------------------------------------------------
// Kernel 4: bilinear grid sample -> x_objT[b,c,hw,m] bf16 (transposed)
// ---------------------------------------------------------------------------
__global__ __launch_bounds__(256) void sampleT_kernel(
        const float* __restrict__ x_tmp, const float* __restrict__ theta,
        unsigned short* __restrict__ x_objT) {
    int idx = blockIdx.x * 256 + threadIdx.x;   // B*C*NPIX*64 = 1,003,520
    int m = idx & 63;
    int hw = (idx >> 6) % NPIX;
    int c = (idx / (64 * NPIX)) % C_CLS;
    int b = idx / (64 * NPIX * C_CLS);
    const float* th = theta + ((size_t)b * C_CLS + c) * 6;
    int w = hw % HWD, h = hw / HWD;
    float fx = -1.f + w * (2.f / 13.f);
    float fy = -1.f + h * (2.f / 13.f);
    float gxn = th[0] * fx + th[1] * fy + th[2];
    float gyn = th[3] * fx + th[4] * fy + th[5];
    float gx = (gxn + 1.f) * 0.5f * (HWD - 1);
    float gy = (gyn + 1.f) * 0.5f * (HWD - 1);
    float x0f = floorf(gx), y0f = floorf(gy);
    int x0 = (int)x0f, y0 = (int)y0f;
    int x1 = x0 + 1, y1 = y0 + 1;
    const float* img = x_tmp + (((size_t)b * C_CLS + c) * M_DIM + m) * NPIX;

    auto gat = [&](int yi, int xi) -> float {
        bool v = (yi >= 0) & (yi < HWD) & (xi >= 0) & (xi < HWD);
        int yc = min(max(yi, 0), HWD - 1);
        int xc = min(max(xi, 0), HWD - 1);
        return v ? img[yc * HWD + xc] : 0.f;
    };
    float xw1 = (float)x1 - gx, xw0 = gx - (float)x0;
    float yw1 = (float)y1 - gy, yw0 = gy - (float)y0;
    float val = gat(y0, x0) * xw1 * yw1 + gat(y0, x1) * xw0 * yw1 +
                gat(y1, x0) * xw1 * yw0 + gat(y1, x1) * xw0 * yw0;
    x_objT[(((size_t)b * C_CLS + c) * NPIX + hw) * 64 + m] = f2bf(val);
}

// ---------------------------------------------------------------------------
// Kernel 5: relation via MFMA. Block=(k,c,b), 4 waves. Wg read fp32, cvt once.
// ---------------------------------------------------------------------------
#define MP 136
__global__ __launch_bounds__(256) void relation_mfma_kernel(
        const unsigned short* __restrict__ x_objT,
        const float* __restrict__ Wg,
        float* __restrict__ partial) {
    __shared__ unsigned short Xs[208 * MP];   // 56,576 B
    const int k = blockIdx.x;
    const int c = blockIdx.y;
    const int b = blockIdx.z;
    const int kj = (k < c) ? k : k + 1;
    const int tid = threadIdx.x;
    const int lane = tid & 63;
    const int wv = tid >> 6;
    const int l15 = lane & 15;
    const int lq = lane >> 4;

    bf16x8s AF[2][4];
    const float* wgb = Wg + (((size_t)c * K_REL + k) * U_DIM) * (2 * M_DIM);
#pragma unroll
    for (int ut = 0; ut < 2; ut++) {
        int u = wv * 32 + ut * 16 + l15;
#pragma unroll
        for (int ks = 0; ks < 4; ks++)
            AF[ut][ks] = cvt8(wgb + (size_t)u * 128 + ks * 32 + lq * 8);
    }

    const unsigned short* xc = x_objT + ((size_t)(b * C_CLS + c)) * NPIX * 64;
    const unsigned short* xk = x_objT + ((size_t)(b * C_CLS + kj)) * NPIX * 64;
#pragma unroll
    for (int it = 0; it < 13; it++) {
        int i = tid + it * 256;            // 0..3327
        int hw = i >> 4, ch = i & 15;
        uint4v v = {0, 0, 0, 0};
        if (hw < NPIX) {
            const unsigned short* src = (ch < 8 ? xc : xk) + (size_t)hw * 64 + (ch & 7) * 8;
            v = *(const uint4v*)src;
        }
        *(uint4v*)(&Xs[hw * MP + ch * 8]) = v;
    }
    __syncthreads();

    float csum[2][4];
#pragma unroll
    for (int ut = 0; ut < 2; ut++)
#pragma unroll
        for (int r = 0; r < 4; r++) csum[ut][r] = 0.f;

    for (int t = 0; t < 13; t++) {
        bf16x8s BF[4];
#pragma unroll
        for (int ks = 0; ks < 4; ks++)
            BF[ks] = *(const bf16x8s*)(&Xs[(t * 16 + l15) * MP + ks * 32 + lq * 8]);
        f32x4 acc0 = {0.f, 0.f, 0.f, 0.f}, acc1 = {0.f, 0.f, 0.f, 0.f};
#pragma unroll
        for (int ks = 0; ks < 4; ks++) {
            acc0 = __builtin_amdgcn_mfma_f32_16x16x32_bf16(AF[0][ks], BF[ks], acc0, 0, 0, 0);
            acc1 = __builtin_amdgcn_mfma_f32_16x16x32_bf16(AF[1][ks], BF[ks], acc1, 0, 0, 0);
        }
#pragma unroll
        for (int r = 0; r < 4; r++) {
            csum[0][r] += fmaxf(acc0[r], 0.f);
            csum[1][r] += fmaxf(acc1[r], 0.f);
        }
    }
#pragma unroll
    for (int mask = 1; mask < 16; mask <<= 1) {
#pragma unroll
        for (int ut = 0; ut < 2; ut++)
#pragma unroll
            for (int r = 0; r < 4; r++)
                csum[ut][r] += __shfl_xor(csum[ut][r], mask, 64);
    }
    if (l15 == 0) {
        float* pp = partial + (((size_t)b * C_CLS + c) * K_REL + k) * U_DIM;
#pragma unroll
        for (int ut = 0; ut < 2; ut++)
#pragma unroll
            for (int r = 0; r < 4; r++)
                pp[wv * 32 + ut * 16 + lq * 4 + r] = csum[ut][r];
    }
}

// ---------------------------------------------------------------------------
// Kernel 6: out[b,c]
// ---------------------------------------------------------------------------
__global__ __launch_bounds__(128) void final_kernel(
        const float* __restrict__ partial, const float* __restrict__ wphi,
        const float* __restrict__ bphi, float* __restrict__ out) {
    int bc = blockIdx.x;
    int u = threadIdx.x;
    float s = 0.f;
    for (int k = 0; k < K_REL; k++)
        s += partial[((size_t)bc * K_REL + k) * U_DIM + u];
    s *= wphi[u];
    __shared__ float red[128];
    red[u] = s;
    __syncthreads();
    for (int off = 64; off > 0; off >>= 1) {
        if (u < off) red[u] += red[u + off];
        __syncthreads();
    }
    if (u == 0) out[bc] = red[0] / (float)NPIX + bphi[0];
}

// ---------------------------------------------------------------------------
extern "C" void kernel_launch(void* const* d_in, const int* in_sizes, int n_in,
                              void* d_out, int out_size, void* d_ws, size_t ws_size,
                              hipStream_t stream) {
    const float* x    = (const float*)d_in[0];
    const float* Wp   = (const float*)d_in[1];
    const float* Wstn = (const float*)d_in[2];
    const float* bstn = (const float*)d_in[3];
    const float* Wg   = (const float*)d_in[4];
    const float* wphi = (const float*)d_in[5];
    const float* bphi = (const float*)d_in[6];
    float* out = (float*)d_out;
    char* wsb = (char*)d_ws;

    float* x_tmp           = (float*)(wsb);                      // 4,014,080 B
    unsigned short* xTb    = (unsigned short*)(wsb + 4014080);   // 3,407,872 B
    float* pooled          = (float*)(wsb + 7421952);            // 1,003,520 B
    float* theta           = (float*)(wsb + 8425472);            //     1,920 B
    float* partial         = (float*)(wsb + 8427392);            //   778,240 B
    unsigned short* x_objT = (unsigned short*)(wsb + 9205632);   // 2,007,040 B
    // total 11,212,672 B

    zero_kernel<<<980, 256, 0, stream>>>(x_tmp);
    xt_kernel<<<dim3(32, 4), 256, 0, stream>>>(x, xTb);
    gemm1_mfma_kernel<<<dim3(20, 4, 2), 256, 0, stream>>>(xTb, Wp, x_tmp);
    pool_kernel<<<980, 256, 0, stream>>>(x_tmp, pooled);
    theta_kernel<<<80, 256, 0, stream>>>(pooled, Wstn, bstn, theta);
    sampleT_kernel<<<3920, 256, 0, stream>>>(x_tmp, theta, x_objT);
    dim3 gr(K_REL, C_CLS, B_SZ);
    relation_mfma_kernel<<<gr, 256, 0, stream>>>(x_objT, Wg, partial);
    final_kernel<<<80, 128, 0, stream>>>(partial, wphi, bphi, out);
}

// Round 5
// 84.466 us; speedup vs baseline: 9.9897x; 1.1819x over previous
//
#include <hip/hip_runtime.h>

#define FEAT 2048
#define HWD 14
#define NPIX 196          // 14*14
#define C_CLS 20
#define M_DIM 64
#define U_DIM 128
#define B_SZ 4
#define K_REL 19          // C-1
#define NPOOL 49          // 7*7

typedef __attribute__((ext_vector_type(8))) short bf16x8s;
typedef __attribute__((ext_vector_type(8))) unsigned short ushort8v;
typedef __attribute__((ext_vector_type(4))) float f32x4;
typedef __attribute__((ext_vector_type(4))) unsigned int uint4v;

__device__ inline unsigned short f2bf(float f) {
    unsigned u = __builtin_bit_cast(unsigned, f);
    unsigned r = (u + 0x7FFF + ((u >> 16) & 1)) >> 16;   // RNE
    return (unsigned short)r;
}

// ---------------------------------------------------------------------------
// Kernel 1: prep. blocks 0..127: x[b][f][hw] f32 -> xTb[b][hw(208 pad)][f] bf16
//           blocks 128..1023: elementwise cvt Wg->Wgb, Wp->Wpb (bf16)
// ---------------------------------------------------------------------------
__global__ __launch_bounds__(256) void prep_kernel(
        const float* __restrict__ x, const float* __restrict__ Wg,
        const float* __restrict__ Wp,
        unsigned short* __restrict__ xTb, unsigned short* __restrict__ Wgb,
        unsigned short* __restrict__ Wpb) {
    __shared__ unsigned short T[64][210];
    const int blk = blockIdx.x;
    const int tid = threadIdx.x;
    if (blk < 128) {
        const int k0 = (blk & 31) * 64;
        const int b = blk >> 5;
        const float* xb = x + ((size_t)b * FEAT + k0) * NPIX;
        for (int i = tid; i < 64 * NPIX; i += 256) {
            int kk = i / NPIX, hw = i - kk * NPIX;
            T[kk][hw] = f2bf(xb[(size_t)kk * NPIX + hw]);
        }
        __syncthreads();
        for (int i = tid; i < 208 * 8; i += 256) {
            int hw = i >> 3, ch = i & 7;
            ushort8v o;
#pragma unroll
            for (int j = 0; j < 8; j++)
                o[j] = (hw < NPIX) ? T[ch * 8 + j][hw] : (unsigned short)0;
            *(ushort8v*)(xTb + ((size_t)b * 208 + hw) * FEAT + k0 + ch * 8) = o;
        }
    } else {
        const int NWG4 = C_CLS * K_REL * U_DIM * 2 * M_DIM / 4;   // 1,556,480
        const int NTOT = NWG4 + C_CLS * M_DIM * FEAT / 4;         // +655,360
        for (int gi = (blk - 128) * 256 + tid; gi < NTOT; gi += 896 * 256) {
            const float* src; unsigned short* dst; int li;
            if (gi < NWG4) { src = Wg; dst = Wgb; li = gi; }
            else           { src = Wp; dst = Wpb; li = gi - NWG4; }
            float4 v = *(const float4*)(src + (size_t)li * 4);
            ushort4 o;
            o.x = f2bf(v.x); o.y = f2bf(v.y); o.z = f2bf(v.z); o.w = f2bf(v.w);
            *(ushort4*)(dst + (size_t)li * 4) = o;
        }
    }
}

// ---------------------------------------------------------------------------
// Kernel 2: FUSED gemm + pool + theta + grid-sample per (c,b) slice.
// Phase A: 64x208 = Wpb[c] (64x2048) * xTb[b] (2048x208) via MFMA, acc in reg.
// Phase B: acc -> LDS xs[64][209] fp32 (stride 209: odd -> conflict-free gathers)
// Phase C: pool 2x2 relu -> pooled[3136] (LDS)
// Phase D: theta[6] = pooled . Wstn[c] + bstn[c]  (block reduction)
// Phase E: bilinear sample from xs -> x_objT[b,c,hw,m] bf16
// 8 waves: wr = wave&3 -> 16-row tile; ch = wave>>2 -> col tiles 0..6 / 7..12.
// ---------------------------------------------------------------------------
#define KP2 72
__global__ __launch_bounds__(512) void fused_kernel(
        const unsigned short* __restrict__ xTb,
        const unsigned short* __restrict__ Wpb,
        const float* __restrict__ Wstn,
        const float* __restrict__ bstn,
        unsigned short* __restrict__ x_objT) {
    __shared__ __align__(16) char smem[78336];
    unsigned short (*Xs)[208 * KP2] = (unsigned short (*)[208 * KP2])smem; // 59,904 B
    float* xs     = (float*)smem;              // [64][209] = 53,504 B
    float* pooled = (float*)(smem + 53504);    // [3136]    = 12,544 B
    float* red    = (float*)(smem + 66048);    // [6][512]  = 12,288 B

    const int c = blockIdx.x, b = blockIdx.y;
    const int tid = threadIdx.x;
    const int lane = tid & 63, wv = tid >> 6;
    const int l15 = lane & 15, lq = lane >> 4;
    const int wr = wv & 3;
    const int ch = wv >> 2;
    const int toff = ch * 7;          // col tiles toff .. toff+NT-1

    const unsigned short* xb = xTb + (size_t)b * 208 * FEAT;
    const unsigned short* wb = Wpb + ((size_t)(c * M_DIM + wr * 16 + l15)) * FEAT + lq * 8;

    uint4v sreg[4];
    auto g_issue = [&](int s) {
#pragma unroll
        for (int it = 0; it < 4; it++) {
            int i = tid + it * 512;
            if (i < 1664)
                sreg[it] = *(const uint4v*)(xb + (size_t)(i >> 3) * FEAT + s * 64 + (i & 7) * 8);
        }
    };
    auto l_write = [&](int buf) {
#pragma unroll
        for (int it = 0; it < 4; it++) {
            int i = tid + it * 512;
            if (i < 1664)
                *(uint4v*)(&Xs[buf][(i >> 3) * KP2 + (i & 7) * 8]) = sreg[it];
        }
    };

    f32x4 acc[7];
#pragma unroll
    for (int t = 0; t < 7; t++) acc[t] = (f32x4){0.f, 0.f, 0.f, 0.f};

    g_issue(0);
    bf16x8s AF0 = *(const bf16x8s*)(wb);
    bf16x8s AF1 = *(const bf16x8s*)(wb + 32);
    l_write(0);
    __syncthreads();

    const int NSTEP = 32;
    for (int s = 0; s < NSTEP; s++) {
        if (s + 1 < NSTEP) g_issue(s + 1);
        bf16x8s A0 = AF0, A1 = AF1;
        if (s + 1 < NSTEP) {
            AF0 = *(const bf16x8s*)(wb + (s + 1) * 64);
            AF1 = *(const bf16x8s*)(wb + (s + 1) * 64 + 32);
        }
        const unsigned short* Xb = Xs[s & 1];
#pragma unroll
        for (int t = 0; t < 7; t++) {
            int tt = toff + t;
            if (tt < 13) {
                bf16x8s B0 = *(const bf16x8s*)(&Xb[(tt * 16 + l15) * KP2 + lq * 8]);
                bf16x8s B1 = *(const bf16x8s*)(&Xb[(tt * 16 + l15) * KP2 + 32 + lq * 8]);
                acc[t] = __builtin_amdgcn_mfma_f32_16x16x32_bf16(A0, B0, acc[t], 0, 0, 0);
                acc[t] = __builtin_amdgcn_mfma_f32_16x16x32_bf16(A1, B1, acc[t], 0, 0, 0);
            }
        }
        if (s + 1 < NSTEP) l_write((s + 1) & 1);
        __syncthreads();
    }

    // Phase B: acc -> xs[row][col], row = wr*16+lq*4+r, col = tt*16+l15
#pragma unroll
    for (int t = 0; t < 7; t++) {
        int tt = toff + t;
        if (tt < 13) {
#pragma unroll
            for (int r = 0; r < 4; r++)
                xs[(wr * 16 + lq * 4 + r) * 209 + tt * 16 + l15] = acc[t][r];
        }
    }
    __syncthreads();

    // Phase C: pooled[m*49 + ph*7 + pw] = relu(max2x2)
    for (int i = tid; i < 3136; i += 512) {
        int m = i / NPOOL, p = i - m * NPOOL;
        int ph = p / 7, pw = p - ph * 7;
        const float* bp = &xs[m * 209 + ph * 2 * HWD + pw * 2];
        float v = fmaxf(fmaxf(bp[0], bp[1]), fmaxf(bp[HWD], bp[HWD + 1]));
        pooled[i] = fmaxf(v, 0.f);
    }
    __syncthreads();

    // Phase D: theta
    float sj[6] = {0, 0, 0, 0, 0, 0};
#pragma unroll
    for (int it = 0; it < 7; it++) {
        int kk = tid + it * 512;
        if (kk < 3136) {
            float f = pooled[kk];
#pragma unroll
            for (int j = 0; j < 6; j++)
                sj[j] += f * Wstn[((size_t)c * 6 + j) * 3136 + kk];
        }
    }
#pragma unroll
    for (int j = 0; j < 6; j++) red[j * 512 + tid] = sj[j];
    __syncthreads();
    for (int off = 256; off > 0; off >>= 1) {
        if (tid < off) {
#pragma unroll
            for (int j = 0; j < 6; j++)
                red[j * 512 + tid] += red[j * 512 + tid + off];
        }
        __syncthreads();
    }
    float th[6];
#pragma unroll
    for (int j = 0; j < 6; j++) th[j] = red[j * 512] + bstn[c * 6 + j];

    // Phase E: bilinear sample from xs; store x_objT[b,c,hw,m] bf16
    const int m = tid & 63;
    const int hwg = tid >> 6;                  // 0..7
    unsigned short* ob = x_objT + ((size_t)(b * C_CLS + c) * NPIX) * 64 + m;
    const float* xrow = &xs[m * 209];
    for (int it = 0; it < 25; it++) {
        int hw = hwg + it * 8;
        if (hw >= NPIX) break;                 // wave-uniform
        int h = hw / HWD, w = hw - h * HWD;
        float fx = -1.f + w * (2.f / 13.f);
        float fy = -1.f + h * (2.f / 13.f);
        float gxn = th[0] * fx + th[1] * fy + th[2];
        float gyn = th[3] * fx + th[4] * fy + th[5];
        float gx = (gxn + 1.f) * 0.5f * (HWD - 1);
        float gy = (gyn + 1.f) * 0.5f * (HWD - 1);
        float x0f = floorf(gx), y0f = floorf(gy);
        int x0 = (int)x0f, y0 = (int)y0f;
        int x1 = x0 + 1, y1 = y0 + 1;
        auto gat = [&](int yi, int xi) -> float {
            bool v = (yi >= 0) & (yi < HWD) & (xi >= 0) & (xi < HWD);
            int yc = min(max(yi, 0), HWD - 1);
            int xc = min(max(xi, 0), HWD - 1);
            return v ? xrow[yc * HWD + xc] : 0.f;
        };
        float xw1 = (float)x1 - gx, xw0 = gx - (float)x0;
        float yw1 = (float)y1 - gy, yw0 = gy - (float)y0;
        float val = gat(y0, x0) * xw1 * yw1 + gat(y0, x1) * xw0 * yw1 +
                    gat(y1, x0) * xw1 * yw0 + gat(y1, x1) * xw0 * yw0;
        ob[(size_t)hw * 64] = f2bf(val);
    }
}

// ---------------------------------------------------------------------------
// Kernel 3: relation via MFMA (bf16 Wgb). Block=(k,c,b), 4 waves.
// ---------------------------------------------------------------------------
#define MP 136
__global__ __launch_bounds__(256) void relation_mfma_kernel(
        const unsigned short* __restrict__ x_objT,
        const unsigned short* __restrict__ Wgb,
        float* __restrict__ partial) {
    __shared__ unsigned short Xs[208 * MP];   // 56,576 B
    const int k = blockIdx.x;
    const int c = blockIdx.y;
    const int b = blockIdx.z;
    const int kj = (k < c) ? k : k + 1;
    const int tid = threadIdx.x;
    const int lane = tid & 63;
    const int wv = tid >> 6;
    const int l15 = lane & 15;
    const int lq = lane >> 4;

    bf16x8s AF[2][4];
    const unsigned short* wgb = Wgb + (((size_t)c * K_REL + k) * U_DIM) * (2 * M_DIM);
#pragma unroll
    for (int ut = 0; ut < 2; ut++) {
        int u = wv * 32 + ut * 16 + l15;
#pragma unroll
        for (int ks = 0; ks < 4; ks++)
            AF[ut][ks] = *(const bf16x8s*)(wgb + (size_t)u * 128 + ks * 32 + lq * 8);
    }

    const unsigned short* xc = x_objT + ((size_t)(b * C_CLS + c)) * NPIX * 64;
    const unsigned short* xk = x_objT + ((size_t)(b * C_CLS + kj)) * NPIX * 64;
#pragma unroll
    for (int it = 0; it < 13; it++) {
        int i = tid + it * 256;            // 0..3327
        int hw = i >> 4, ch = i & 15;
        uint4v v = {0, 0, 0, 0};
        if (hw < NPIX) {
            const unsigned short* src = (ch < 8 ? xc : xk) + (size_t)hw * 64 + (ch & 7) * 8;
            v = *(const uint4v*)src;
        }
        *(uint4v*)(&Xs[hw * MP + ch * 8]) = v;
    }
    __syncthreads();

    float csum[2][4];
#pragma unroll
    for (int ut = 0; ut < 2; ut++)
#pragma unroll
        for (int r = 0; r < 4; r++) csum[ut][r] = 0.f;

    for (int t = 0; t < 13; t++) {
        bf16x8s BF[4];
#pragma unroll
        for (int ks = 0; ks < 4; ks++)
            BF[ks] = *(const bf16x8s*)(&Xs[(t * 16 + l15) * MP + ks * 32 + lq * 8]);
        f32x4 acc0 = {0.f, 0.f, 0.f, 0.f}, acc1 = {0.f, 0.f, 0.f, 0.f};
#pragma unroll
        for (int ks = 0; ks < 4; ks++) {
            acc0 = __builtin_amdgcn_mfma_f32_16x16x32_bf16(AF[0][ks], BF[ks], acc0, 0, 0, 0);
            acc1 = __builtin_amdgcn_mfma_f32_16x16x32_bf16(AF[1][ks], BF[ks], acc1, 0, 0, 0);
        }
#pragma unroll
        for (int r = 0; r < 4; r++) {
            csum[0][r] += fmaxf(acc0[r], 0.f);
            csum[1][r] += fmaxf(acc1[r], 0.f);
        }
    }
#pragma unroll
    for (int mask = 1; mask < 16; mask <<= 1) {
#pragma unroll
        for (int ut = 0; ut < 2; ut++)
#pragma unroll
            for (int r = 0; r < 4; r++)
                csum[ut][r] += __shfl_xor(csum[ut][r], mask, 64);
    }
    if (l15 == 0) {
        float* pp = partial + (((size_t)b * C_CLS + c) * K_REL + k) * U_DIM;
#pragma unroll
        for (int ut = 0; ut < 2; ut++)
#pragma unroll
            for (int r = 0; r < 4; r++)
                pp[wv * 32 + ut * 16 + lq * 4 + r] = csum[ut][r];
    }
}

// ---------------------------------------------------------------------------
// Kernel 4: out[b,c]
// ---------------------------------------------------------------------------
__global__ __launch_bounds__(128) void final_kernel(
        const float* __restrict__ partial, const float* __restrict__ wphi,
        const float* __restrict__ bphi, float* __restrict__ out) {
    int bc = blockIdx.x;
    int u = threadIdx.x;
    float s = 0.f;
    for (int k = 0; k < K_REL; k++)
        s += partial[((size_t)bc * K_REL + k) * U_DIM + u];
    s *= wphi[u];
    __shared__ float red[128];
    red[u] = s;
    __syncthreads();
    for (int off = 64; off > 0; off >>= 1) {
        if (u < off) red[u] += red[u + off];
        __syncthreads();
    }
    if (u == 0) out[bc] = red[0] / (float)NPIX + bphi[0];
}

// ---------------------------------------------------------------------------
extern "C" void kernel_launch(void* const* d_in, const int* in_sizes, int n_in,
                              void* d_out, int out_size, void* d_ws, size_t ws_size,
                              hipStream_t stream) {
    const float* x    = (const float*)d_in[0];
    const float* Wp   = (const float*)d_in[1];
    const float* Wstn = (const float*)d_in[2];
    const float* bstn = (const float*)d_in[3];
    const float* Wg   = (const float*)d_in[4];
    const float* wphi = (const float*)d_in[5];
    const float* bphi = (const float*)d_in[6];
    float* out = (float*)d_out;
    char* wsb = (char*)d_ws;

    unsigned short* xTb    = (unsigned short*)(wsb);              //  3,407,872 B
    unsigned short* Wgb    = (unsigned short*)(wsb + 3407872);    // 12,451,840 B
    unsigned short* Wpb    = (unsigned short*)(wsb + 15859712);   //  5,242,880 B
    unsigned short* x_objT = (unsigned short*)(wsb + 21102592);   //  2,007,040 B
    float* partial         = (float*)(wsb + 23109632);            //    778,240 B
    // total 23,887,872 B

    prep_kernel<<<1024, 256, 0, stream>>>(x, Wg, Wp, xTb, Wgb, Wpb);
    fused_kernel<<<dim3(C_CLS, B_SZ), 512, 0, stream>>>(xTb, Wpb, Wstn, bstn, x_objT);
    relation_mfma_kernel<<<dim3(K_REL, C_CLS, B_SZ), 256, 0, stream>>>(x_objT, Wgb, partial);
    final_kernel<<<80, 128, 0, stream>>>(partial, wphi, bphi, out);
}

// Round 6
// 74.687 us; speedup vs baseline: 11.2978x; 1.1309x over previous
//
#include <hip/hip_runtime.h>

#define FEAT 2048
#define HWD 14
#define NPIX 196          // 14*14
#define C_CLS 20
#define M_DIM 64
#define U_DIM 128
#define B_SZ 4
#define K_REL 19          // C-1
#define NPOOL 49          // 7*7

typedef __attribute__((ext_vector_type(8))) short bf16x8s;
typedef __attribute__((ext_vector_type(8))) unsigned short ushort8v;
typedef __attribute__((ext_vector_type(4))) float f32x4;
typedef __attribute__((ext_vector_type(4))) unsigned int uint4v;

__device__ inline unsigned short f2bf(float f) {
    unsigned u = __builtin_bit_cast(unsigned, f);
    unsigned r = (u + 0x7FFF + ((u >> 16) & 1)) >> 16;   // RNE
    return (unsigned short)r;
}

__device__ inline bf16x8s cvt8(const float* __restrict__ p) {
    float4 lo = *(const float4*)p;
    float4 hi = *(const float4*)(p + 4);
    bf16x8s r;
    r[0] = (short)f2bf(lo.x); r[1] = (short)f2bf(lo.y);
    r[2] = (short)f2bf(lo.z); r[3] = (short)f2bf(lo.w);
    r[4] = (short)f2bf(hi.x); r[5] = (short)f2bf(hi.y);
    r[6] = (short)f2bf(hi.z); r[7] = (short)f2bf(hi.w);
    return r;
}

// ---------------------------------------------------------------------------
// Kernel 1: prep.
//  blocks 0..127 (b = blk>>5, s = blk&31): x[b][s*64..+63][hw] ->
//     xts[b][s][i=ch*208+row][8]  (staging order for fused g_issue; row>=196 -> 0)
//  blocks 128..1023:
//     (a) Awp[c*256 + s*8 + fi][lane][8] = Wp[c][m=rt*16+(lane&15)]
//           [k=s*64+f*32+(lane>>4)*8+j], fi = rt*2+f   (A-fragment order)
//     (b) Wgb = bf16(Wg) linear
// ---------------------------------------------------------------------------
__global__ __launch_bounds__(256) void prep_kernel(
        const float* __restrict__ x, const float* __restrict__ Wg,
        const float* __restrict__ Wp,
        unsigned short* __restrict__ xts, unsigned short* __restrict__ Wgb,
        unsigned short* __restrict__ Awp) {
    __shared__ unsigned short T[64][210];
    const int blk = blockIdx.x;
    const int tid = threadIdx.x;
    if (blk < 128) {
        const int b = blk >> 5;
        const int s = blk & 31;
        const float* xb = x + ((size_t)b * FEAT + s * 64) * NPIX;
        for (int i = tid; i < 64 * NPIX; i += 256) {
            int kk = i / NPIX, hw = i - kk * NPIX;
            T[kk][hw] = f2bf(xb[(size_t)kk * NPIX + hw]);
        }
        __syncthreads();
        unsigned short* ob = xts + ((size_t)(b * 32 + s)) * 1664 * 8;
        for (int i = tid; i < 1664; i += 256) {
            int ch = i / 208, row = i - ch * 208;
            ushort8v o;
#pragma unroll
            for (int j = 0; j < 8; j++)
                o[j] = (row < NPIX) ? T[ch * 8 + j][row] : (unsigned short)0;
            *(ushort8v*)(ob + (size_t)i * 8) = o;
        }
    } else {
        const int lane = tid & 63;
        // (a) Awp: 5120 rows (c:20 x s:32 x fi:8), one row per wave
        int gw = (blk - 128) * 4 + (tid >> 6);
        for (int r = gw; r < 5120; r += 896 * 4) {
            int c = r >> 8;
            int rem = r & 255;
            int s = rem >> 3, fi = rem & 7;
            int rt = fi >> 1, f = fi & 1;
            int m = rt * 16 + (lane & 15);
            int k = s * 64 + f * 32 + (lane >> 4) * 8;
            bf16x8s v = cvt8(Wp + ((size_t)(c * M_DIM + m)) * FEAT + k);
            *(bf16x8s*)(Awp + ((size_t)r * 64 + lane) * 8) = v;
        }
        // (b) Wgb cast
        const int NWG4 = C_CLS * K_REL * U_DIM * 2 * M_DIM / 4;   // 1,556,480
        for (int gi = (blk - 128) * 256 + tid; gi < NWG4; gi += 896 * 256) {
            float4 v = *(const float4*)(Wg + (size_t)gi * 4);
            ushort4 o;
            o.x = f2bf(v.x); o.y = f2bf(v.y); o.z = f2bf(v.z); o.w = f2bf(v.w);
            *(ushort4*)(Wgb + (size_t)gi * 4) = o;
        }
    }
}

// ---------------------------------------------------------------------------
// Kernel 2: FUSED gemm + pool + theta + grid-sample per (c,b) slice.
// 8 waves = 2 row-groups (32 rows) x 4 col-groups (tiles {4,3,3,3} of 13).
// BK=64, 32 K-steps, LDS dbuf + depth-2 register staging prefetch,
// A-fragments from pre-swizzled Awp (contiguous, L1-broadcast), prefetch 1.
// ---------------------------------------------------------------------------
#define KP2 72
__global__ __launch_bounds__(512) void fused_kernel(
        const unsigned short* __restrict__ xts,
        const unsigned short* __restrict__ Awp,
        const float* __restrict__ Wstn,
        const float* __restrict__ bstn,
        unsigned short* __restrict__ x_objT) {
    __shared__ __align__(16) char smem[78336];
    unsigned short* Xs0 = (unsigned short*)smem;            // 208*72*2 = 29,952 B
    unsigned short* Xs1 = (unsigned short*)(smem + 29952);  // 29,952 B
    float* xs     = (float*)smem;              // [64][209] = 53,504 B
    float* pooled = (float*)(smem + 53504);    // [3136]    = 12,544 B
    float* red    = (float*)(smem + 66048);    // [6][512]  = 12,288 B

    const int c = blockIdx.x, b = blockIdx.y;
    const int tid = threadIdx.x;
    const int lane = tid & 63, wv = tid >> 6;
    const int l15 = lane & 15, lq = lane >> 4;
    const int rg = wv & 1;            // row group: rows rg*32 .. +31
    const int cg = wv >> 1;           // col group
    const int cs = (cg == 0) ? 0 : (3 * cg + 1);   // {0,4,7,10}
    const int nct = (cg == 0) ? 4 : 3;

    const unsigned short* xsrc = xts + (size_t)b * 32 * 1664 * 8;
    const unsigned short* asrc = Awp + (size_t)c * 256 * 64 * 8;

    // per-thread staging geometry (independent of step)
    int ldsoff[4]; size_t goff[4]; bool gvalid[4];
#pragma unroll
    for (int it = 0; it < 4; it++) {
        int i = it * 512 + tid;
        gvalid[it] = (i < 1664);
        int ii = gvalid[it] ? i : 0;
        int ch = ii / 208, row = ii - ch * 208;
        ldsoff[it] = row * KP2 + ch * 8;
        goff[it] = (size_t)ii * 8;
    }

    uint4v SA[4], SB[4];
    auto g_issue = [&](int s, uint4v (&S)[4]) {
        const unsigned short* src = xsrc + (size_t)s * 1664 * 8;
#pragma unroll
        for (int it = 0; it < 4; it++)
            if (gvalid[it]) S[it] = *(const uint4v*)(src + goff[it]);
    };
    auto l_write = [&](unsigned short* buf, uint4v (&S)[4]) {
#pragma unroll
        for (int it = 0; it < 4; it++)
            if (gvalid[it]) *(uint4v*)(buf + ldsoff[it]) = S[it];
    };

    bf16x8s AF[2][2], AFn[2][2];
    auto aload = [&](int s, bf16x8s (&A)[2][2]) {
#pragma unroll
        for (int rt2 = 0; rt2 < 2; rt2++)
#pragma unroll
            for (int f = 0; f < 2; f++) {
                int fi = (rg * 2 + rt2) * 2 + f;
                A[rt2][f] = *(const bf16x8s*)(asrc + (((size_t)s * 8 + fi) * 64 + lane) * 8);
            }
    };

    f32x4 acc[2][4];
#pragma unroll
    for (int rt2 = 0; rt2 < 2; rt2++)
#pragma unroll
        for (int q = 0; q < 4; q++) acc[rt2][q] = (f32x4){0.f, 0.f, 0.f, 0.f};

    auto compute = [&](const unsigned short* Xb, bf16x8s (&A)[2][2]) {
#pragma unroll
        for (int q = 0; q < 4; q++) {
            if (q < nct) {
                int tt = cs + q;
#pragma unroll
                for (int f = 0; f < 2; f++) {
                    bf16x8s Bf = *(const bf16x8s*)(&Xb[(tt * 16 + l15) * KP2 + f * 32 + lq * 8]);
                    acc[0][q] = __builtin_amdgcn_mfma_f32_16x16x32_bf16(A[0][f], Bf, acc[0][q], 0, 0, 0);
                    acc[1][q] = __builtin_amdgcn_mfma_f32_16x16x32_bf16(A[1][f], Bf, acc[1][q], 0, 0, 0);
                }
            }
        }
    };

    // prolog
    g_issue(0, SA);
    g_issue(1, SB);
    aload(0, AF);
    l_write(Xs0, SA);
    __syncthreads();

    for (int sp = 0; sp < 16; sp++) {
        // even step s0 = 2*sp (buf Xs0, frags AF)
        aload(2 * sp + 1, AFn);
        compute(Xs0, AF);
        if (sp < 15) g_issue(2 * sp + 2, SA);
        l_write(Xs1, SB);
        __syncthreads();
        // odd step s1 = 2*sp+1 (buf Xs1, frags AFn)
        if (sp < 15) aload(2 * sp + 2, AF);
        compute(Xs1, AFn);
        if (sp < 15) {
            g_issue(2 * sp + 3, SB);
            l_write(Xs0, SA);
        }
        __syncthreads();
    }

    // Phase B: acc -> xs[row][col]
#pragma unroll
    for (int q = 0; q < 4; q++) {
        if (q < nct) {
            int tt = cs + q;
#pragma unroll
            for (int rt2 = 0; rt2 < 2; rt2++) {
                int row0 = (rg * 2 + rt2) * 16 + lq * 4;
#pragma unroll
                for (int r = 0; r < 4; r++)
                    xs[(row0 + r) * 209 + tt * 16 + l15] = acc[rt2][q][r];
            }
        }
    }
    __syncthreads();

    // Phase C: pooled[m*49 + ph*7 + pw] = relu(max2x2)
    for (int i = tid; i < 3136; i += 512) {
        int m = i / NPOOL, p = i - m * NPOOL;
        int ph = p / 7, pw = p - ph * 7;
        const float* bp = &xs[m * 209 + ph * 2 * HWD + pw * 2];
        float v = fmaxf(fmaxf(bp[0], bp[1]), fmaxf(bp[HWD], bp[HWD + 1]));
        pooled[i] = fmaxf(v, 0.f);
    }
    __syncthreads();

    // Phase D: theta
    float sj[6] = {0, 0, 0, 0, 0, 0};
#pragma unroll
    for (int it = 0; it < 7; it++) {
        int kk = tid + it * 512;
        if (kk < 3136) {
            float f = pooled[kk];
#pragma unroll
            for (int j = 0; j < 6; j++)
                sj[j] += f * Wstn[((size_t)c * 6 + j) * 3136 + kk];
        }
    }
#pragma unroll
    for (int j = 0; j < 6; j++) red[j * 512 + tid] = sj[j];
    __syncthreads();
    for (int off = 256; off > 0; off >>= 1) {
        if (tid < off) {
#pragma unroll
            for (int j = 0; j < 6; j++)
                red[j * 512 + tid] += red[j * 512 + tid + off];
        }
        __syncthreads();
    }
    float th[6];
#pragma unroll
    for (int j = 0; j < 6; j++) th[j] = red[j * 512] + bstn[c * 6 + j];

    // Phase E: bilinear sample from xs; store x_objT[b,c,hw,m] bf16
    const int m = tid & 63;
    const int hwg = tid >> 6;                  // 0..7
    unsigned short* ob = x_objT + ((size_t)(b * C_CLS + c) * NPIX) * 64 + m;
    const float* xrow = &xs[m * 209];
    for (int it = 0; it < 25; it++) {
        int hw = hwg + it * 8;
        if (hw >= NPIX) break;                 // wave-uniform
        int h = hw / HWD, w = hw - h * HWD;
        float fx = -1.f + w * (2.f / 13.f);
        float fy = -1.f + h * (2.f / 13.f);
        float gxn = th[0] * fx + th[1] * fy + th[2];
        float gyn = th[3] * fx + th[4] * fy + th[5];
        float gx = (gxn + 1.f) * 0.5f * (HWD - 1);
        float gy = (gyn + 1.f) * 0.5f * (HWD - 1);
        float x0f = floorf(gx), y0f = floorf(gy);
        int x0 = (int)x0f, y0 = (int)y0f;
        int x1 = x0 + 1, y1 = y0 + 1;
        auto gat = [&](int yi, int xi) -> float {
            bool v = (yi >= 0) & (yi < HWD) & (xi >= 0) & (xi < HWD);
            int yc = min(max(yi, 0), HWD - 1);
            int xc = min(max(xi, 0), HWD - 1);
            return v ? xrow[yc * HWD + xc] : 0.f;
        };
        float xw1 = (float)x1 - gx, xw0 = gx - (float)x0;
        float yw1 = (float)y1 - gy, yw0 = gy - (float)y0;
        float val = gat(y0, x0) * xw1 * yw1 + gat(y0, x1) * xw0 * yw1 +
                    gat(y1, x0) * xw1 * yw0 + gat(y1, x1) * xw0 * yw0;
        ob[(size_t)hw * 64] = f2bf(val);
    }
}

// ---------------------------------------------------------------------------
// Kernel 3: relation via MFMA (bf16 Wgb). Block=(k,c,b), 4 waves.
// ---------------------------------------------------------------------------
#define MP 136
__global__ __launch_bounds__(256) void relation_mfma_kernel(
        const unsigned short* __restrict__ x_objT,
        const unsigned short* __restrict__ Wgb,
        float* __restrict__ partial) {
    __shared__ unsigned short Xs[208 * MP];   // 56,576 B
    const int k = blockIdx.x;
    const int c = blockIdx.y;
    const int b = blockIdx.z;
    const int kj = (k < c) ? k : k + 1;
    const int tid = threadIdx.x;
    const int lane = tid & 63;
    const int wv = tid >> 6;
    const int l15 = lane & 15;
    const int lq = lane >> 4;

    bf16x8s AF[2][4];
    const unsigned short* wgb = Wgb + (((size_t)c * K_REL + k) * U_DIM) * (2 * M_DIM);
#pragma unroll
    for (int ut = 0; ut < 2; ut++) {
        int u = wv * 32 + ut * 16 + l15;
#pragma unroll
        for (int ks = 0; ks < 4; ks++)
            AF[ut][ks] = *(const bf16x8s*)(wgb + (size_t)u * 128 + ks * 32 + lq * 8);
    }

    const unsigned short* xc = x_objT + ((size_t)(b * C_CLS + c)) * NPIX * 64;
    const unsigned short* xk = x_objT + ((size_t)(b * C_CLS + kj)) * NPIX * 64;
#pragma unroll
    for (int it = 0; it < 13; it++) {
        int i = tid + it * 256;            // 0..3327
        int hw = i >> 4, ch = i & 15;
        uint4v v = {0, 0, 0, 0};
        if (hw < NPIX) {
            const unsigned short* src = (ch < 8 ? xc : xk) + (size_t)hw * 64 + (ch & 7) * 8;
            v = *(const uint4v*)src;
        }
        *(uint4v*)(&Xs[hw * MP + ch * 8]) = v;
    }
    __syncthreads();

    float csum[2][4];
#pragma unroll
    for (int ut = 0; ut < 2; ut++)
#pragma unroll
        for (int r = 0; r < 4; r++) csum[ut][r] = 0.f;

    for (int t = 0; t < 13; t++) {
        bf16x8s BF[4];
#pragma unroll
        for (int ks = 0; ks < 4; ks++)
            BF[ks] = *(const bf16x8s*)(&Xs[(t * 16 + l15) * MP + ks * 32 + lq * 8]);
        f32x4 acc0 = {0.f, 0.f, 0.f, 0.f}, acc1 = {0.f, 0.f, 0.f, 0.f};
#pragma unroll
        for (int ks = 0; ks < 4; ks++) {
            acc0 = __builtin_amdgcn_mfma_f32_16x16x32_bf16(AF[0][ks], BF[ks], acc0, 0, 0, 0);
            acc1 = __builtin_amdgcn_mfma_f32_16x16x32_bf16(AF[1][ks], BF[ks], acc1, 0, 0, 0);
        }
#pragma unroll
        for (int r = 0; r < 4; r++) {
            csum[0][r] += fmaxf(acc0[r], 0.f);
            csum[1][r] += fmaxf(acc1[r], 0.f);
        }
    }
#pragma unroll
    for (int mask = 1; mask < 16; mask <<= 1) {
#pragma unroll
        for (int ut = 0; ut < 2; ut++)
#pragma unroll
            for (int r = 0; r < 4; r++)
                csum[ut][r] += __shfl_xor(csum[ut][r], mask, 64);
    }
    if (l15 == 0) {
        float* pp = partial + (((size_t)b * C_CLS + c) * K_REL + k) * U_DIM;
#pragma unroll
        for (int ut = 0; ut < 2; ut++)
#pragma unroll
            for (int r = 0; r < 4; r++)
                pp[wv * 32 + ut * 16 + lq * 4 + r] = csum[ut][r];
    }
}

// ---------------------------------------------------------------------------
// Kernel 4: out[b,c]
// ---------------------------------------------------------------------------
__global__ __launch_bounds__(128) void final_kernel(
        const float* __restrict__ partial, const float* __restrict__ wphi,
        const float* __restrict__ bphi, float* __restrict__ out) {
    int bc = blockIdx.x;
    int u = threadIdx.x;
    float s = 0.f;
    for (int k = 0; k < K_REL; k++)
        s += partial[((size_t)bc * K_REL + k) * U_DIM + u];
    s *= wphi[u];
    __shared__ float red[128];
    red[u] = s;
    __syncthreads();
    for (int off = 64; off > 0; off >>= 1) {
        if (u < off) red[u] += red[u + off];
        __syncthreads();
    }
    if (u == 0) out[bc] = red[0] / (float)NPIX + bphi[0];
}

// ---------------------------------------------------------------------------
extern "C" void kernel_launch(void* const* d_in, const int* in_sizes, int n_in,
                              void* d_out, int out_size, void* d_ws, size_t ws_size,
                              hipStream_t stream) {
    const float* x    = (const float*)d_in[0];
    const float* Wp   = (const float*)d_in[1];
    const float* Wstn = (const float*)d_in[2];
    const float* bstn = (const float*)d_in[3];
    const float* Wg   = (const float*)d_in[4];
    const float* wphi = (const float*)d_in[5];
    const float* bphi = (const float*)d_in[6];
    float* out = (float*)d_out;
    char* wsb = (char*)d_ws;

    unsigned short* xts    = (unsigned short*)(wsb);              //  3,407,872 B
    unsigned short* Wgb    = (unsigned short*)(wsb + 3407872);    // 12,451,840 B
    unsigned short* Awp    = (unsigned short*)(wsb + 15859712);   //  5,242,880 B
    unsigned short* x_objT = (unsigned short*)(wsb + 21102592);   //  2,007,040 B
    float* partial         = (float*)(wsb + 23109632);            //    778,240 B
    // total 23,887,872 B

    prep_kernel<<<1024, 256, 0, stream>>>(x, Wg, Wp, xts, Wgb, Awp);
    fused_kernel<<<dim3(C_CLS, B_SZ), 512, 0, stream>>>(xts, Awp, Wstn, bstn, x_objT);
    relation_mfma_kernel<<<dim3(K_REL, C_CLS, B_SZ), 256, 0, stream>>>(x_objT, Wgb, partial);
    final_kernel<<<80, 128, 0, stream>>>(partial, wphi, bphi, out);
}